// Round 9
// baseline (1335.169 us; speedup 1.0000x reference)
//
#include <hip/hip_runtime.h>
#include <math.h>

#define DIVUP(a,b) (((a)+(b)-1)/(b))

typedef __bf16 bf16x8 __attribute__((ext_vector_type(8)));
typedef __bf16 bf16x4 __attribute__((ext_vector_type(4)));
typedef float  f32x4  __attribute__((ext_vector_type(4)));

// ---------------------------------------------------------------------------
// Implicit-GEMM conv, NHWC, split-bf16 3-MFMA. BM=256, BN=64, BK=32.
// 256 thr = 4 waves; wave wv owns rows [256bx+64wv, +64) = 4 row-tiles q;
// 48 MFMA / wave / K-step in 3 dependency-spaced passes.
// A: direct global->VGPR in frag layout (no cross-wave reuse -> no LDS).
// B: cooperatively staged to LDS [64][40] (R7 layout), double-buffered,
//    ONE barrier per K-step; all 4 waves share the panel.
// A frags ping-pong via 2x-unrolled regions with named register sets.
// XCD-aware bijective block swizzle (m204). POOL=1: quad-M + fused maxpool.
// Emits per-block per-channel (sum,sumsq) partials (invalid rows exact 0).
// ---------------------------------------------------------------------------
template<int POOL, int C1>
__global__ __launch_bounds__(256) void conv_mfma(
    const __bf16* __restrict__ inH, const __bf16* __restrict__ inL, long inZstride,
    const __bf16* __restrict__ wtH, const __bf16* __restrict__ wtL,
    float* __restrict__ out, long outZstride, float2* __restrict__ part,
    int HinP, int WinP, int Hout, int Wout, int Cout, int M, int niter,
    int H2, int W2, int H2c, int W2c)
{
    __shared__ __align__(16) char smem[20480];   // B dbuf: 2 x (H 5120 + L 5120)
    float2* red = (float2*)smem;                 // [64][17] overlay after K-loop

    // ---- bijective XCD swizzle (m204) ----
    int bx;
    {
        int n = gridDim.x, orig = blockIdx.x;
        int q = n >> 3, r = n & 7;
        int xcd = orig & 7, idx = orig >> 3;
        bx = (xcd < r ? xcd * (q + 1) : r * (q + 1) + (xcd - r) * q) + idx;
    }

    const int tid  = threadIdx.x;
    const int wv   = tid >> 6;
    const int ln15 = tid & 15;
    const int lhi  = (tid >> 4) & 3;
    const int sn   = tid & 63;        // B-stage: n row this thread stages
    const int skb  = tid >> 6;        // B-stage: kb slot
    const int sdst = sn * 40 + skb * 8;

    const __bf16* ipH = inH + (size_t)blockIdx.z * inZstride;
    const __bf16* ipL = inL + (size_t)blockIdx.z * inZstride;

    auto geom = [&](int mA, int& base, bool& valid) {
        int nb, h, w;
        if (POOL) {
            int r = mA & 3, quad = mA >> 2;
            int cpi = H2c * W2c;
            nb = quad / cpi;
            int rem = quad - nb * cpi;
            int h2 = rem / W2c, w2 = rem - h2 * W2c;
            h = h2 * 2 + (r >> 1); w = w2 * 2 + (r & 1);
            valid = (mA < M) && (h < Hout) && (w < Wout);
        } else {
            int HW = Hout * Wout;
            valid = mA < M;
            int mm = valid ? mA : 0;
            nb = mm / HW;
            int rem = mm - nb * HW;
            h = rem / Wout; w = rem - h * Wout;
        }
        if (!valid) { nb = 0; h = 0; w = 0; }
        if (C1) base = ((nb * 256 + h) * 256 + w) * 4;
        else    base = ((nb * HinP + h) * WinP + w) * 64;
    };

    int abase[4]; bool av[4];
#pragma unroll
    for (int q = 0; q < 4; ++q)
        geom(bx * 256 + wv * 64 + q * 16 + ln15, abase[q], av[q]);

    const __bf16* wpH = wtH + (size_t)blockIdx.z * niter * 2048;
    const __bf16* wpL = wtL + (size_t)blockIdx.z * niter * 2048;

    bf16x8 zero8;
#pragma unroll
    for (int j = 0; j < 8; ++j) zero8[j] = (__bf16)0.0f;

    auto loadA = [&](int it, bf16x8 (&aH)[4], bf16x8 (&aL)[4]) {
        int off;
        if (C1) off = it * 1024 + lhi * 8;
        else { int tap = it >> 1; int kh = tap / 3, kw = tap - 3 * kh;
               off = (kh * WinP + kw) * 64 + (it & 1) * 32 + lhi * 8; }
#pragma unroll
        for (int q = 0; q < 4; ++q) {
            aH[q] = av[q] ? *(const bf16x8*)(ipH + abase[q] + off) : zero8;
            aL[q] = av[q] ? *(const bf16x8*)(ipL + abase[q] + off) : zero8;
        }
    };

    f32x4 acc[4][4] = {};
    bf16x8 a0H[4], a0L[4], a1H[4], a1L[4];
    bf16x8 sbH, sbL;

    // ---- prologue: buf0 <- B(0); a0 <- A(0); a1 <- A(1); sb <- B(1) ----
    {
        size_t a = (size_t)(skb * 64 + sn) * 8;
        bf16x8 h = *(const bf16x8*)(wpH + a);
        bf16x8 l = *(const bf16x8*)(wpL + a);
        __bf16* wd = (__bf16*)smem + sdst;
        *(bf16x8*)wd = h;
        *(bf16x8*)(wd + 2560) = l;
        loadA(0, a0H, a0L);
        if (niter > 1) {
            loadA(1, a1H, a1L);
            size_t a1i = (size_t)((4 + skb) * 64 + sn) * 8;
            sbH = *(const bf16x8*)(wpH + a1i);
            sbL = *(const bf16x8*)(wpL + a1i);
        }
        __syncthreads();
    }

#define REGION(IT, CUR, AH, AL)                                                   \
    {                                                                             \
        const int itc = (IT);                                                     \
        if (itc + 1 < niter) {                                                    \
            __bf16* wd = (__bf16*)(smem + ((CUR) ^ 1) * 10240) + sdst;            \
            *(bf16x8*)wd = sbH;                                                   \
            *(bf16x8*)(wd + 2560) = sbL;                                          \
        }                                                                         \
        const __bf16* rb = (const __bf16*)(smem + (CUR) * 10240);                 \
        bf16x8 bHf[4], bLf[4];                                                    \
        _Pragma("unroll")                                                         \
        for (int t = 0; t < 4; ++t) {                                             \
            bHf[t] = *(const bf16x8*)(rb + (t * 16 + ln15) * 40 + lhi * 8);       \
            bLf[t] = *(const bf16x8*)(rb + 2560 + (t * 16 + ln15) * 40 + lhi * 8);\
        }                                                                         \
        if (itc + 2 < niter) {                                                    \
            size_t a = (size_t)(((itc + 2) * 4 + skb) * 64 + sn) * 8;             \
            sbH = *(const bf16x8*)(wpH + a);                                      \
            sbL = *(const bf16x8*)(wpL + a);                                      \
        }                                                                         \
        _Pragma("unroll")                                                         \
        for (int t = 0; t < 4; ++t)                                               \
            _Pragma("unroll")                                                     \
            for (int q = 0; q < 4; ++q)                                           \
                acc[q][t] = __builtin_amdgcn_mfma_f32_16x16x32_bf16(AH[q], bHf[t], acc[q][t], 0, 0, 0); \
        _Pragma("unroll")                                                         \
        for (int t = 0; t < 4; ++t)                                               \
            _Pragma("unroll")                                                     \
            for (int q = 0; q < 4; ++q)                                           \
                acc[q][t] = __builtin_amdgcn_mfma_f32_16x16x32_bf16(AL[q], bHf[t], acc[q][t], 0, 0, 0); \
        _Pragma("unroll")                                                         \
        for (int t = 0; t < 4; ++t)                                               \
            _Pragma("unroll")                                                     \
            for (int q = 0; q < 4; ++q)                                           \
                acc[q][t] = __builtin_amdgcn_mfma_f32_16x16x32_bf16(AH[q], bLf[t], acc[q][t], 0, 0, 0); \
        if (itc + 2 < niter) loadA(itc + 2, AH, AL);                              \
        __syncthreads();                                                          \
    }

    for (int it = 0; it < niter; it += 2) {
        REGION(it, 0, a0H, a0L);
        if (it + 1 < niter) REGION(it + 1, 1, a1H, a1L);
    }
#undef REGION

    // ---- per-block per-channel (sum,sumsq) partials ----
#pragma unroll
    for (int t = 0; t < 4; ++t) {
        float s = 0.f, s2 = 0.f;
#pragma unroll
        for (int q = 0; q < 4; ++q)
#pragma unroll
            for (int r = 0; r < 4; ++r) { float v = acc[q][t][r]; s += v; s2 += v * v; }
        red[(ln15 + 16 * t) * 17 + (wv * 4 + lhi)] = make_float2(s, s2);
    }
    __syncthreads();
    if (tid < 64) {
        float s = 0.f, s2 = 0.f;
#pragma unroll
        for (int q = 0; q < 16; ++q) { float2 v = red[tid * 17 + q]; s += v.x; s2 += v.y; }
        part[((size_t)blockIdx.z * 64 + tid) * gridDim.x + bx] = make_float2(s, s2);
    }

    // ---- NHWC output ----
    float* zout = out + (size_t)blockIdx.z * outZstride;
#pragma unroll
    for (int q = 0; q < 4; ++q) {
        const int mbase = bx * 256 + wv * 64 + q * 16 + lhi * 4;
        if (POOL) {
            if (mbase < M) {
                int quad = mbase >> 2;
                int cpi  = H2c * W2c;
                int nb2  = quad / cpi;
                int rem  = quad - nb2 * cpi;
                int h2 = rem / W2c, w2 = rem - h2 * W2c;
                if (h2 < H2 && w2 < W2) {
                    float* op = zout + ((size_t)(nb2 * H2 + h2) * W2 + w2) * Cout;
#pragma unroll
                    for (int t = 0; t < 4; ++t) {
                        int n = ln15 + 16 * t;
                        if (n < Cout) {
                            float mx = fmaxf(fmaxf(acc[q][t][0], acc[q][t][1]),
                                             fmaxf(acc[q][t][2], acc[q][t][3]));
                            op[n] = mx;
                        }
                    }
                }
            }
        } else {
#pragma unroll
            for (int r = 0; r < 4; ++r) {
                int m = mbase + r;
                if (m < M) {
                    float* op = zout + (size_t)m * Cout;
#pragma unroll
                    for (int t = 0; t < 4; ++t) {
                        int n = ln15 + 16 * t;
                        if (n < Cout) op[n] = acc[q][t][r];
                    }
                }
            }
        }
    }
}

// partials -> (mean, rsqrt(var+eps)) per (z,channel)
__global__ __launch_bounds__(256) void bn_finalize(const float2* __restrict__ part,
                                                   int nblkx, double Ninv,
                                                   float2* __restrict__ stats)
{
    __shared__ double sh[512];
    const int zc = blockIdx.x, tid = threadIdx.x;
    const float2* p = part + (size_t)zc * nblkx;
    double s = 0, s2 = 0;
    for (int i = tid; i < nblkx; i += 256) { s += p[i].x; s2 += p[i].y; }
    sh[tid] = s; sh[256 + tid] = s2;
    __syncthreads();
    for (int st = 128; st > 0; st >>= 1) {
        if (tid < st) { sh[tid] += sh[tid + st]; sh[256 + tid] += sh[256 + tid + st]; }
        __syncthreads();
    }
    if (tid == 0) {
        float mean = (float)(sh[0] * Ninv);
        float var  = (float)(sh[256] * Ninv - (double)mean * (double)mean);
        if (var < 0.f) var = 0.f;
        stats[zc] = make_float2(mean, rsqrtf(var + 1e-5f));
    }
}

// raw NHWC fp32 + stats -> padded NHWC bf16 hi/lo with zero border.
__global__ void bn_split(const float* __restrict__ raw, const float2* __restrict__ stats,
                         __bf16* __restrict__ outH, __bf16* __restrict__ outL,
                         int H, int W, int total)
{
    int idx = blockIdx.x * 256 + threadIdx.x;
    if (idx >= total) return;
    const int Hp = H + 2, Wp = W + 2;
    int c4 = idx & 15;
    int t  = idx >> 4;
    int wp = t % Wp; t /= Wp;
    int hp = t % Hp; int img = t / Hp;
    size_t o = (((size_t)img * Hp + hp) * Wp + wp) * 64 + c4 * 4;
    bf16x4 hi, lo;
    if (hp == 0 || hp == Hp - 1 || wp == 0 || wp == Wp - 1) {
#pragma unroll
        for (int j = 0; j < 4; ++j) { hi[j] = (__bf16)0.f; lo[j] = (__bf16)0.f; }
    } else {
        float4 v = *(const float4*)(raw + (((size_t)img * H + (hp - 1)) * W + (wp - 1)) * 64 + c4 * 4);
        const float2* st = stats + (img >> 4) * 64 + c4 * 4;
        float vv[4] = {v.x, v.y, v.z, v.w};
#pragma unroll
        for (int j = 0; j < 4; ++j) {
            float2 s = st[j];
            float r = fmaxf((vv[j] - s.x) * s.y, 0.f);
            __bf16 hh = (__bf16)r;
            hi[j] = hh; lo[j] = (__bf16)(r - (float)hh);
        }
    }
    *(bf16x4*)(outH + o) = hi;
    *(bf16x4*)(outL + o) = lo;
}

// pooled NHWC [P][16][H][W][64] + stats + d -> XB padded hi/lo [C][16][Hp][Wp][64]
__global__ void mix_split(const float* __restrict__ pooled, const float2* __restrict__ stats,
                          const float* __restrict__ d,
                          __bf16* __restrict__ outH, __bf16* __restrict__ outL,
                          int H, int W, int P, long strideP, int total)
{
    int idx = blockIdx.x * 256 + threadIdx.x;
    if (idx >= total) return;
    const int Hp = H + 2, Wp = W + 2;
    int c4 = idx & 15;
    int t  = idx >> 4;
    int wp = t % Wp; t /= Wp;
    int hp = t % Hp; t /= Hp;
    int n  = t & 15;
    int cc = t >> 4;
    size_t o = (((size_t)(cc * 16 + n) * Hp + hp) * Wp + wp) * 64 + c4 * 4;
    bf16x4 hi, lo;
    if (hp == 0 || hp == Hp - 1 || wp == 0 || wp == Wp - 1) {
#pragma unroll
        for (int j = 0; j < 4; ++j) { hi[j] = (__bf16)0.f; lo[j] = (__bf16)0.f; }
    } else {
        float a[4] = {0.f, 0.f, 0.f, 0.f};
        const float* pb = pooled + (((size_t)n * H + (hp - 1)) * W + (wp - 1)) * 64 + c4 * 4;
        for (int p = 0; p < P; ++p) {
            float4 v = *(const float4*)(pb + (size_t)p * strideP);
            const float2* st = stats + p * 64 + c4 * 4;
            float dc = d[cc * P + p];
            float vv[4] = {v.x, v.y, v.z, v.w};
#pragma unroll
            for (int j = 0; j < 4; ++j) {
                float2 s = st[j];
                a[j] = fmaf(dc, fmaxf((vv[j] - s.x) * s.y, 0.f), a[j]);
            }
        }
#pragma unroll
        for (int j = 0; j < 4; ++j) {
            __bf16 hh = (__bf16)a[j];
            hi[j] = hh; lo[j] = (__bf16)(a[j] - (float)hh);
        }
    }
    *(bf16x4*)(outH + o) = hi;
    *(bf16x4*)(outL + o) = lo;
}

// L3 mix: pooled [16][16][7][7][32] -> XB3 fp32 [40][16][7][7][32]
__global__ void mix_last(const float* __restrict__ pooled, const float2* __restrict__ stats,
                         const float* __restrict__ d, float* __restrict__ out, int total)
{
    int idx = blockIdx.x * 256 + threadIdx.x;
    if (idx >= total) return;
    int c  = idx & 31;
    int t  = idx >> 5;
    int hw = t % 49; t /= 49;
    int n  = t & 15;
    int a  = t >> 4;
    float acc = 0.f;
    const float* pb = pooled + ((size_t)n * 49 + hw) * 32 + c;
    for (int p = 0; p < 16; ++p) {
        float2 s = stats[p * 64 + c];
        acc = fmaf(d[a * 16 + p], fmaxf((pb[(size_t)p * 25088] - s.x) * s.y, 0.f), acc);
    }
    out[idx] = acc;
}

// x NCHW [16][3][256][256] -> packed NHWC4 hi/lo [16][256][256][4]
__global__ void prep_x(const float* __restrict__ x, __bf16* __restrict__ xH,
                       __bf16* __restrict__ xL)
{
    int idx = blockIdx.x * 256 + threadIdx.x;   // 16*65536
    if (idx >= 16 * 65536) return;
    int n = idx >> 16, hw = idx & 65535;
    bf16x4 hi, lo;
#pragma unroll
    for (int ci = 0; ci < 3; ++ci) {
        float v = x[((size_t)n * 3 + ci) * 65536 + hw];
        __bf16 hh = (__bf16)v;
        hi[ci] = hh; lo[ci] = (__bf16)(v - (float)hh);
    }
    hi[3] = (__bf16)0.f; lo[3] = (__bf16)0.f;
    *(bf16x4*)(xH + (size_t)idx * 4) = hi;
    *(bf16x4*)(xL + (size_t)idx * 4) = lo;
}

// conv1 weights [64][3][7][7] -> hi/lo panels [28 kblk][64][8], k=kh*32+kw*4+ci
__global__ void wtrans1(const float* __restrict__ w, __bf16* __restrict__ wH,
                        __bf16* __restrict__ wL)
{
    int i = blockIdx.x * 256 + threadIdx.x;
    if (i >= 28 * 512) return;
    int j = i & 7, n = (i >> 3) & 63, kb = i >> 9;
    int k = kb * 8 + j;
    int kh = k >> 5, r = k & 31, kw = r >> 2, ci = r & 3;
    float v = (kw < 7 && ci < 3) ? w[((n * 3 + ci) * 7 + kh) * 7 + kw] : 0.f;
    __bf16 hh = (__bf16)v;
    wH[i] = hh; wL[i] = (__bf16)(v - (float)hh);
}

// 3x3 weights [P][Cout][64][3][3] -> hi/lo panels [p][72 kblk][64][8],
// k = (kh*3+kw)*64 + ci
__global__ void wtrans3(const float* __restrict__ w, __bf16* __restrict__ wH,
                        __bf16* __restrict__ wL, int P, int Cout)
{
    int total = P * 72 * 512;
    for (int i = blockIdx.x * 256 + threadIdx.x; i < total; i += gridDim.x * 256) {
        int j = i & 7, n = (i >> 3) & 63, kb = (i >> 9) % 72, p = (i >> 9) / 72;
        int k = kb * 8 + j;
        int ci = k & 63, tap = k >> 6, kh = tap / 3, kw = tap - 3 * kh;
        float v = (n < Cout) ? w[(((size_t)(p * Cout + n)) * 64 + ci) * 9 + kh * 3 + kw] : 0.f;
        __bf16 hh = (__bf16)v;
        wH[i] = hh; wL[i] = (__bf16)(v - (float)hh);
    }
}

// d = softmax_p( log(softmax_p(br*2)) / t ) for all 4 layers
__global__ void dcalc(const float* __restrict__ br0, const float* __restrict__ br1,
                      const float* __restrict__ br2, const float* __restrict__ br3,
                      const void* __restrict__ tptr, float* __restrict__ D)
{
    const int L = blockIdx.x;
    const float* br; int C, P, off;
    if      (L == 0) { br = br0; C = 4;  P = 2;  off = 0;   }
    else if (L == 1) { br = br1; C = 8;  P = 4;  off = 8;   }
    else if (L == 2) { br = br2; C = 16; P = 8;  off = 40;  }
    else             { br = br3; C = 40; P = 16; off = 168; }
    int ti = *(const int*)tptr;
    float t = (ti > 0 && ti < 1000000) ? (float)ti : *(const float*)tptr;
    const int c = threadIdx.x;
    if (c >= C) return;
    float u[16];
    float mx = -1e30f;
#pragma unroll
    for (int p = 0; p < 16; ++p) if (p < P) { u[p] = br[c * P + p] * 2.0f; mx = fmaxf(mx, u[p]); }
    float se = 0.f;
#pragma unroll
    for (int p = 0; p < 16; ++p) if (p < P) se += expf(u[p] - mx);
    float lse = mx + logf(se);
    float mx2 = -1e30f;
#pragma unroll
    for (int p = 0; p < 16; ++p) if (p < P) { u[p] = (u[p] - lse) / t; mx2 = fmaxf(mx2, u[p]); }
    float se2 = 0.f;
#pragma unroll
    for (int p = 0; p < 16; ++p) if (p < P) { u[p] = expf(u[p] - mx2); se2 += u[p]; }
#pragma unroll
    for (int p = 0; p < 16; ++p) if (p < P) D[off + c * P + p] = u[p] / se2;
}

// h1[a,b,i] = relu( sum_f f[a,b,f]*fw1[a,f,i] + fb1[a,i] ); f stored (h,w,c),
// fw1 indexed (c,h,w)
__global__ __launch_bounds__(128) void fc1_k(const float* __restrict__ f,
                                             const float* __restrict__ w1,
                                             const float* __restrict__ b1,
                                             float* __restrict__ h1)
{
    const int a = blockIdx.x >> 4;
    const int b = blockIdx.x & 15;
    const int i = threadIdx.x;
    const float* fv = f + ((size_t)a * 16 + b) * 1568;
    const float* wv = w1 + (size_t)a * 1568 * 128 + i;
    float acc = b1[a * 128 + i];
    for (int hw = 0; hw < 49; ++hw)
        for (int c = 0; c < 32; ++c)
            acc = fmaf(fv[hw * 32 + c], wv[(size_t)(c * 49 + hw) * 128], acc);
    h1[((size_t)a * 16 + b) * 128 + i] = fmaxf(acc, 0.f);
}

__global__ __launch_bounds__(128) void fc23_k(const float* __restrict__ h1,
                                              const float* __restrict__ w2,
                                              const float* __restrict__ b2,
                                              const float* __restrict__ w3,
                                              const float* __restrict__ b3,
                                              float* __restrict__ out)
{
    __shared__ float sh1[16][128];
    __shared__ float sh2[16][128];
    const int a = blockIdx.x;
    const int i = threadIdx.x;
    for (int b = 0; b < 16; ++b) sh1[b][i] = h1[((size_t)a * 16 + b) * 128 + i];
    __syncthreads();
    float acc[16];
#pragma unroll
    for (int b = 0; b < 16; ++b) acc[b] = b2[a * 128 + i];
    for (int ff = 0; ff < 128; ++ff) {
        float wv = w2[((size_t)a * 128 + ff) * 128 + i];
#pragma unroll
        for (int b = 0; b < 16; ++b) acc[b] = fmaf(sh1[b][ff], wv, acc[b]);
    }
    for (int b = 0; b < 16; ++b) sh2[b][i] = fmaxf(acc[b], 0.f);
    __syncthreads();
    if (i < 16) {
        float o = b3[a];
        for (int ff = 0; ff < 128; ++ff) o = fmaf(sh2[i][ff], w3[a * 128 + ff], o);
        out[i * 40 + a] = o;
    }
}

extern "C" void kernel_launch(void* const* d_in, const int* in_sizes, int n_in,
                              void* d_out, int out_size, void* d_ws, size_t ws_size,
                              hipStream_t stream)
{
    (void)in_sizes; (void)n_in;

    const float* x   = (const float*)d_in[0];
    const float* w10 = (const float*)d_in[1];
    const float* wa[4] = {(const float*)d_in[3],  (const float*)d_in[7],
                          (const float*)d_in[11], (const float*)d_in[15]};
    const float* wb[4] = {(const float*)d_in[5],  (const float*)d_in[9],
                          (const float*)d_in[13], (const float*)d_in[17]};
    const float* br[4] = {(const float*)d_in[19], (const float*)d_in[20],
                          (const float*)d_in[21], (const float*)d_in[22]};
    const float* fw1 = (const float*)d_in[23];
    const float* fb1 = (const float*)d_in[24];
    const float* fw2 = (const float*)d_in[25];
    const float* fb2 = (const float*)d_in[26];
    const float* fw3 = (const float*)d_in[27];
    const float* fb3 = (const float*)d_in[28];
    float* out = (float*)d_out;

    const int Pl[4]  = {2, 4, 8, 16};
    const int CBs[4] = {64, 64, 64, 32};

    // ---- workspace arenas (f32 units); total 60,264,704 f32 = 241.06 MB ----
    const size_t NEED = 60264704ull * 4ull;
    if (ws_size < NEED) {
        hipMemsetAsync(d_out, 0, (size_t)out_size * sizeof(float), stream);
        return;
    }
    float* ws = (float*)d_ws;
    size_t o = 0;
    __bf16* WT1H = (__bf16*)(ws + o); o += 7168;   // 14336 bf16
    __bf16* WT1L = (__bf16*)(ws + o); o += 7168;
    __bf16 *WTAH[4], *WTAL[4], *WTBH[4], *WTBL[4];
    for (int L = 0; L < 4; ++L) {                  // P*72*512 bf16 each
        WTAH[L] = (__bf16*)(ws + o); o += (size_t)Pl[L] * 18432;
        WTAL[L] = (__bf16*)(ws + o); o += (size_t)Pl[L] * 18432;
        WTBH[L] = (__bf16*)(ws + o); o += (size_t)Pl[L] * 18432;
        WTBL[L] = (__bf16*)(ws + o); o += (size_t)Pl[L] * 18432;
    }
    float*  D     = ws + o; o += 1024;
    float2* STATS = (float2*)(ws + o); o += 4352;
    float2* STATS_C1 = STATS;
    float2* STATS_A  = STATS + 64;
    float2* STATS_B  = STATS + 1088;
    float*  H1 = ws + o; o += 81920;
    float*  A6 = ws + o; o += 524288;      // small conv partials
    float*  A5 = ws + o; o += 7872512;     // pooled raw / conv1 partials
    float*  A4 = ws + o; o += 16000000;    // raw conv outputs (fp32 NHWC)
    float*  A3 = ws + o; o += 16777216;    // split bufs (hi/lo bf16) / xc
    float*  A2 = ws + o; o += 16777216;    // Y / XB chain

    float2* PART   = (float2*)A6;
    float2* PARTC1 = (float2*)A5;
    __bf16* xcH = (__bf16*)A3;
    __bf16* xcL = (__bf16*)(A3 + 2097152);
    __bf16* A2H = (__bf16*)A2;             // hi at A2[0:], lo after
    __bf16* A2L = (__bf16*)(A2 + 8388608);
    __bf16* A3H = (__bf16*)A3;
    __bf16* A3L = (__bf16*)(A3 + 8388608);

    // ---- weights + mix coefficients + conv1 input prep ----
    prep_x<<<4096, 256, 0, stream>>>(x, xcH, xcL);
    wtrans1<<<56, 256, 0, stream>>>(w10, WT1H, WT1L);
    for (int L = 0; L < 4; ++L) {
        int tA = Pl[L] * 72 * 512;
        wtrans3<<<DIVUP(tA, 256), 256, 0, stream>>>(wa[L], WTAH[L], WTAL[L], Pl[L], 64);
        wtrans3<<<DIVUP(tA, 256), 256, 0, stream>>>(wb[L], WTBH[L], WTBL[L], Pl[L], CBs[L]);
    }
    dcalc<<<4, 64, 0, stream>>>(br[0], br[1], br[2], br[3], d_in[29], D);

    // ---- conv1: xc -> pooled raw A4 [16,125,125,64] + stats ----
    conv_mfma<1, 1><<<dim3(3907, 1, 1), 256, 0, stream>>>(
        xcH, xcL, 0, WT1H, WT1L, A4, 0, PARTC1,
        256, 256, 250, 250, 64, 1000000, 7, 125, 125, 125, 125);
    bn_finalize<<<64, 256, 0, stream>>>(PARTC1, 3907, 1.0 / 1000000.0, STATS_C1);
    // Y = bn_split(A4) -> A2 padded [16][127][127][64]
    bn_split<<<DIVUP(16 * 127 * 127 * 16, 256), 256, 0, stream>>>(
        A4, STATS_C1, A2H, A2L, 125, 125, 16 * 127 * 127 * 16);

    // ---- layer 0 (per parent; Y shared) ----
    for (int p = 0; p < 2; ++p) {
        conv_mfma<0, 0><<<dim3(977, 1, 1), 256, 0, stream>>>(
            A2H, A2L, 0, WTAH[0] + (size_t)p * 36864, WTAL[0] + (size_t)p * 36864,
            A4, 0, PART, 127, 127, 125, 125, 64, 250000, 18, 0, 0, 1, 1);
        bn_finalize<<<64, 256, 0, stream>>>(PART, 977, 1.0 / 250000.0, STATS_A);
        bn_split<<<DIVUP(16 * 127 * 127 * 16, 256), 256, 0, stream>>>(
            A4, STATS_A, A3H, A3L, 125, 125, 16 * 127 * 127 * 16);
        conv_mfma<1, 0><<<dim3(993, 1, 1), 256, 0, stream>>>(
            A3H, A3L, 0, WTBH[0] + (size_t)p * 36864, WTBL[0] + (size_t)p * 36864,
            A5 + (size_t)p * 3936256, 0, PART,
            127, 127, 125, 125, 64, 254016, 18, 62, 62, 63, 63);
        bn_finalize<<<64, 256, 0, stream>>>(PART, 993, 1.0 / 250000.0, STATS_B + p * 64);
    }
    mix_split<<<DIVUP(4 * 16 * 64 * 64 * 16, 256), 256, 0, stream>>>(
        A5, STATS_B, D + 0, A2H, A2L, 62, 62, 2, 3936256, 4 * 16 * 64 * 64 * 16);

    // ---- layer 1 (z=4) ----
    conv_mfma<0, 0><<<dim3(241, 1, 4), 256, 0, stream>>>(
        A2H, A2L, 4194304, WTAH[1], WTAL[1], A4, 3936256, PART,
        64, 64, 62, 62, 64, 61504, 18, 0, 0, 1, 1);
    bn_finalize<<<256, 256, 0, stream>>>(PART, 241, 1.0 / 61504.0, STATS_A);
    bn_split<<<DIVUP(64 * 64 * 64 * 16, 256), 256, 0, stream>>>(
        A4, STATS_A, A3H, A3L, 62, 62, 64 * 64 * 64 * 16);
    conv_mfma<1, 0><<<dim3(241, 1, 4), 256, 0, stream>>>(
        A3H, A3L, 4194304, WTBH[1], WTBL[1], A5, 984064, PART,
        64, 64, 62, 62, 64, 61504, 18, 31, 31, 31, 31);
    bn_finalize<<<256, 256, 0, stream>>>(PART, 241, 1.0 / 61504.0, STATS_B);
    mix_split<<<DIVUP(8 * 16 * 33 * 33 * 16, 256), 256, 0, stream>>>(
        A5, STATS_B, D + 8, A2H, A2L, 31, 31, 4, 984064, 8 * 16 * 33 * 33 * 16);

    // ---- layer 2 (z=8) ----
    conv_mfma<0, 0><<<dim3(61, 1, 8), 256, 0, stream>>>(
        A2H, A2L, 1115136, WTAH[2], WTAL[2], A4, 984064, PART,
        33, 33, 31, 31, 64, 15376, 18, 0, 0, 1, 1);
    bn_finalize<<<512, 256, 0, stream>>>(PART, 61, 1.0 / 15376.0, STATS_A);
    bn_split<<<DIVUP(128 * 33 * 33 * 16, 256), 256, 0, stream>>>(
        A4, STATS_A, A3H, A3L, 31, 31, 128 * 33 * 33 * 16);
    conv_mfma<1, 0><<<dim3(64, 1, 8), 256, 0, stream>>>(
        A3H, A3L, 1115136, WTBH[2], WTBL[2], A5, 230400, PART,
        33, 33, 31, 31, 64, 16384, 18, 15, 15, 16, 16);
    bn_finalize<<<512, 256, 0, stream>>>(PART, 64, 1.0 / 15376.0, STATS_B);
    mix_split<<<DIVUP(16 * 16 * 17 * 17 * 16, 256), 256, 0, stream>>>(
        A5, STATS_B, D + 40, A2H, A2L, 15, 15, 8, 230400, 16 * 16 * 17 * 17 * 16);

    // ---- layer 3 (z=16) ----
    conv_mfma<0, 0><<<dim3(15, 1, 16), 256, 0, stream>>>(
        A2H, A2L, 295936, WTAH[3], WTAL[3], A4, 230400, PART,
        17, 17, 15, 15, 64, 3600, 18, 0, 0, 1, 1);
    bn_finalize<<<1024, 256, 0, stream>>>(PART, 15, 1.0 / 3600.0, STATS_A);
    bn_split<<<DIVUP(256 * 17 * 17 * 16, 256), 256, 0, stream>>>(
        A4, STATS_A, A3H, A3L, 15, 15, 256 * 17 * 17 * 16);
    conv_mfma<1, 0><<<dim3(16, 1, 16), 256, 0, stream>>>(
        A3H, A3L, 295936, WTBH[3], WTBL[3], A5, 25088, PART,
        17, 17, 15, 15, 32, 4096, 18, 7, 7, 8, 8);
    bn_finalize<<<1024, 256, 0, stream>>>(PART, 16, 1.0 / 3600.0, STATS_B);
    mix_last<<<DIVUP(40 * 16 * 49 * 32, 256), 256, 0, stream>>>(
        A5, STATS_B, D + 168, A2, 40 * 16 * 49 * 32);

    // ---- FC heads ----
    fc1_k<<<640, 128, 0, stream>>>(A2, fw1, fb1, H1);
    fc23_k<<<40, 128, 0, stream>>>(H1, fw2, fb2, fw3, fb3, out);
}

// Round 11
// 1171.826 us; speedup vs baseline: 1.1394x; 1.1394x over previous
//
#include <hip/hip_runtime.h>
#include <math.h>

#define DIVUP(a,b) (((a)+(b)-1)/(b))

typedef __bf16 bf16x8 __attribute__((ext_vector_type(8)));
typedef __bf16 bf16x4 __attribute__((ext_vector_type(4)));
typedef float  f32x4  __attribute__((ext_vector_type(4)));

// ---------------------------------------------------------------------------
// Implicit-GEMM conv, NHWC, split-bf16 3-MFMA. BM=128, BN=64, BK=32.
// 256 thr = 4 waves; wave wv owns rows [128bx+32wv, +32) = 2 row-tiles q;
// 24 MFMA / wave / K-step.
// A: direct global->VGPR in frag layout (no cross-wave reuse -> no LDS),
//    double-buffered via named register sets in 2x-unrolled regions.
// B: cooperatively staged to LDS [64][40], double-buffered, ONE barrier
//    per K-step; panel shared by all 4 waves.
// VGPR budget target <=128 (occupancy cliff at 128 -> 16 waves/CU).
// XCD-aware bijective block swizzle (m204). POOL=1: quad-M + fused maxpool.
// Emits per-block per-channel (sum,sumsq) partials (invalid rows exact 0).
// ---------------------------------------------------------------------------
template<int POOL, int C1>
__global__ __launch_bounds__(256) void conv_mfma(
    const __bf16* __restrict__ inH, const __bf16* __restrict__ inL, long inZstride,
    const __bf16* __restrict__ wtH, const __bf16* __restrict__ wtL,
    float* __restrict__ out, long outZstride, float2* __restrict__ part,
    int HinP, int WinP, int Hout, int Wout, int Cout, int M, int niter,
    int H2, int W2, int H2c, int W2c)
{
    __shared__ __align__(16) char smem[20480];   // B dbuf: 2 x (H 5120 + L 5120)
    float2* red = (float2*)smem;                 // [64][17] overlay after K-loop

    // ---- bijective XCD swizzle (m204) ----
    int bx;
    {
        int n = gridDim.x, orig = blockIdx.x;
        int q = n >> 3, r = n & 7;
        int xcd = orig & 7, idx = orig >> 3;
        bx = (xcd < r ? xcd * (q + 1) : r * (q + 1) + (xcd - r) * q) + idx;
    }

    const int tid  = threadIdx.x;
    const int wv   = tid >> 6;
    const int ln15 = tid & 15;
    const int lhi  = (tid >> 4) & 3;
    const int sn   = tid & 63;        // B-stage: n row this thread stages
    const int skb  = tid >> 6;        // B-stage: kb slot
    const int sdst = sn * 40 + skb * 8;

    const __bf16* ipH = inH + (size_t)blockIdx.z * inZstride;
    const __bf16* ipL = inL + (size_t)blockIdx.z * inZstride;

    auto geom = [&](int mA, int& base, bool& valid) {
        int nb, h, w;
        if (POOL) {
            int r = mA & 3, quad = mA >> 2;
            int cpi = H2c * W2c;
            nb = quad / cpi;
            int rem = quad - nb * cpi;
            int h2 = rem / W2c, w2 = rem - h2 * W2c;
            h = h2 * 2 + (r >> 1); w = w2 * 2 + (r & 1);
            valid = (mA < M) && (h < Hout) && (w < Wout);
        } else {
            int HW = Hout * Wout;
            valid = mA < M;
            int mm = valid ? mA : 0;
            nb = mm / HW;
            int rem = mm - nb * HW;
            h = rem / Wout; w = rem - h * Wout;
        }
        if (!valid) { nb = 0; h = 0; w = 0; }
        if (C1) base = ((nb * 256 + h) * 256 + w) * 4;
        else    base = ((nb * HinP + h) * WinP + w) * 64;
    };

    int abase[2]; bool av[2];
#pragma unroll
    for (int q = 0; q < 2; ++q)
        geom(bx * 128 + wv * 32 + q * 16 + ln15, abase[q], av[q]);

    const __bf16* wpH = wtH + (size_t)blockIdx.z * niter * 2048;
    const __bf16* wpL = wtL + (size_t)blockIdx.z * niter * 2048;

    bf16x8 zero8;
#pragma unroll
    for (int j = 0; j < 8; ++j) zero8[j] = (__bf16)0.0f;

    auto loadA = [&](int it, bf16x8 (&aH)[2], bf16x8 (&aL)[2]) {
        int off;
        if (C1) off = it * 1024 + lhi * 8;
        else { int tap = it >> 1; int kh = tap / 3, kw = tap - 3 * kh;
               off = (kh * WinP + kw) * 64 + (it & 1) * 32 + lhi * 8; }
#pragma unroll
        for (int q = 0; q < 2; ++q) {
            aH[q] = av[q] ? *(const bf16x8*)(ipH + abase[q] + off) : zero8;
            aL[q] = av[q] ? *(const bf16x8*)(ipL + abase[q] + off) : zero8;
        }
    };

    f32x4 acc[2][4] = {};
    bf16x8 a0H[2], a0L[2], a1H[2], a1L[2];
    bf16x8 sbH, sbL;

    // ---- prologue: buf0 <- B(0); a0 <- A(0); a1 <- A(1); sb <- B(1) ----
    {
        size_t a = (size_t)(skb * 64 + sn) * 8;
        bf16x8 h = *(const bf16x8*)(wpH + a);
        bf16x8 l = *(const bf16x8*)(wpL + a);
        __bf16* wd = (__bf16*)smem + sdst;
        *(bf16x8*)wd = h;
        *(bf16x8*)(wd + 2560) = l;
        loadA(0, a0H, a0L);
        if (niter > 1) {
            loadA(1, a1H, a1L);
            size_t a1i = (size_t)((4 + skb) * 64 + sn) * 8;
            sbH = *(const bf16x8*)(wpH + a1i);
            sbL = *(const bf16x8*)(wpL + a1i);
        }
        __syncthreads();
    }

#define REGION(IT, CUR, AH, AL)                                                   \
    {                                                                             \
        const int itc = (IT);                                                     \
        if (itc + 1 < niter) {                                                    \
            __bf16* wd = (__bf16*)(smem + ((CUR) ^ 1) * 10240) + sdst;            \
            *(bf16x8*)wd = sbH;                                                   \
            *(bf16x8*)(wd + 2560) = sbL;                                          \
        }                                                                         \
        const __bf16* rb = (const __bf16*)(smem + (CUR) * 10240);                 \
        bf16x8 bHf[4], bLf[4];                                                    \
        _Pragma("unroll")                                                         \
        for (int t = 0; t < 4; ++t) {                                             \
            bHf[t] = *(const bf16x8*)(rb + (t * 16 + ln15) * 40 + lhi * 8);       \
            bLf[t] = *(const bf16x8*)(rb + 2560 + (t * 16 + ln15) * 40 + lhi * 8);\
        }                                                                         \
        if (itc + 2 < niter) {                                                    \
            size_t a = (size_t)(((itc + 2) * 4 + skb) * 64 + sn) * 8;             \
            sbH = *(const bf16x8*)(wpH + a);                                      \
            sbL = *(const bf16x8*)(wpL + a);                                      \
        }                                                                         \
        _Pragma("unroll")                                                         \
        for (int t = 0; t < 4; ++t)                                               \
            _Pragma("unroll")                                                     \
            for (int q = 0; q < 2; ++q)                                           \
                acc[q][t] = __builtin_amdgcn_mfma_f32_16x16x32_bf16(AH[q], bHf[t], acc[q][t], 0, 0, 0); \
        _Pragma("unroll")                                                         \
        for (int t = 0; t < 4; ++t)                                               \
            _Pragma("unroll")                                                     \
            for (int q = 0; q < 2; ++q)                                           \
                acc[q][t] = __builtin_amdgcn_mfma_f32_16x16x32_bf16(AL[q], bHf[t], acc[q][t], 0, 0, 0); \
        _Pragma("unroll")                                                         \
        for (int t = 0; t < 4; ++t)                                               \
            _Pragma("unroll")                                                     \
            for (int q = 0; q < 2; ++q)                                           \
                acc[q][t] = __builtin_amdgcn_mfma_f32_16x16x32_bf16(AH[q], bLf[t], acc[q][t], 0, 0, 0); \
        if (itc + 2 < niter) loadA(itc + 2, AH, AL);                              \
        __syncthreads();                                                          \
    }

    for (int it = 0; it < niter; it += 2) {
        REGION(it, 0, a0H, a0L);
        if (it + 1 < niter) REGION(it + 1, 1, a1H, a1L);
    }
#undef REGION

    // ---- per-block per-channel (sum,sumsq) partials ----
#pragma unroll
    for (int t = 0; t < 4; ++t) {
        float s = 0.f, s2 = 0.f;
#pragma unroll
        for (int q = 0; q < 2; ++q)
#pragma unroll
            for (int r = 0; r < 4; ++r) { float v = acc[q][t][r]; s += v; s2 += v * v; }
        red[(ln15 + 16 * t) * 17 + (wv * 4 + lhi)] = make_float2(s, s2);
    }
    __syncthreads();
    if (tid < 64) {
        float s = 0.f, s2 = 0.f;
#pragma unroll
        for (int q = 0; q < 16; ++q) { float2 v = red[tid * 17 + q]; s += v.x; s2 += v.y; }
        part[((size_t)blockIdx.z * 64 + tid) * gridDim.x + bx] = make_float2(s, s2);
    }

    // ---- NHWC output ----
    float* zout = out + (size_t)blockIdx.z * outZstride;
#pragma unroll
    for (int q = 0; q < 2; ++q) {
        const int mbase = bx * 128 + wv * 32 + q * 16 + lhi * 4;
        if (POOL) {
            if (mbase < M) {
                int quad = mbase >> 2;
                int cpi  = H2c * W2c;
                int nb2  = quad / cpi;
                int rem  = quad - nb2 * cpi;
                int h2 = rem / W2c, w2 = rem - h2 * W2c;
                if (h2 < H2 && w2 < W2) {
                    float* op = zout + ((size_t)(nb2 * H2 + h2) * W2 + w2) * Cout;
#pragma unroll
                    for (int t = 0; t < 4; ++t) {
                        int n = ln15 + 16 * t;
                        if (n < Cout) {
                            float mx = fmaxf(fmaxf(acc[q][t][0], acc[q][t][1]),
                                             fmaxf(acc[q][t][2], acc[q][t][3]));
                            op[n] = mx;
                        }
                    }
                }
            }
        } else {
#pragma unroll
            for (int r = 0; r < 4; ++r) {
                int m = mbase + r;
                if (m < M) {
                    float* op = zout + (size_t)m * Cout;
#pragma unroll
                    for (int t = 0; t < 4; ++t) {
                        int n = ln15 + 16 * t;
                        if (n < Cout) op[n] = acc[q][t][r];
                    }
                }
            }
        }
    }
}

// partials -> (mean, rsqrt(var+eps)) per (z,channel)
__global__ __launch_bounds__(256) void bn_finalize(const float2* __restrict__ part,
                                                   int nblkx, double Ninv,
                                                   float2* __restrict__ stats)
{
    __shared__ double sh[512];
    const int zc = blockIdx.x, tid = threadIdx.x;
    const float2* p = part + (size_t)zc * nblkx;
    double s = 0, s2 = 0;
    for (int i = tid; i < nblkx; i += 256) { s += p[i].x; s2 += p[i].y; }
    sh[tid] = s; sh[256 + tid] = s2;
    __syncthreads();
    for (int st = 128; st > 0; st >>= 1) {
        if (tid < st) { sh[tid] += sh[tid + st]; sh[256 + tid] += sh[256 + tid + st]; }
        __syncthreads();
    }
    if (tid == 0) {
        float mean = (float)(sh[0] * Ninv);
        float var  = (float)(sh[256] * Ninv - (double)mean * (double)mean);
        if (var < 0.f) var = 0.f;
        stats[zc] = make_float2(mean, rsqrtf(var + 1e-5f));
    }
}

// raw NHWC fp32 + stats -> padded NHWC bf16 hi/lo with zero border.
__global__ void bn_split(const float* __restrict__ raw, const float2* __restrict__ stats,
                         __bf16* __restrict__ outH, __bf16* __restrict__ outL,
                         int H, int W, int total)
{
    int idx = blockIdx.x * 256 + threadIdx.x;
    if (idx >= total) return;
    const int Hp = H + 2, Wp = W + 2;
    int c4 = idx & 15;
    int t  = idx >> 4;
    int wp = t % Wp; t /= Wp;
    int hp = t % Hp; int img = t / Hp;
    size_t o = (((size_t)img * Hp + hp) * Wp + wp) * 64 + c4 * 4;
    bf16x4 hi, lo;
    if (hp == 0 || hp == Hp - 1 || wp == 0 || wp == Wp - 1) {
#pragma unroll
        for (int j = 0; j < 4; ++j) { hi[j] = (__bf16)0.f; lo[j] = (__bf16)0.f; }
    } else {
        float4 v = *(const float4*)(raw + (((size_t)img * H + (hp - 1)) * W + (wp - 1)) * 64 + c4 * 4);
        const float2* st = stats + (img >> 4) * 64 + c4 * 4;
        float vv[4] = {v.x, v.y, v.z, v.w};
#pragma unroll
        for (int j = 0; j < 4; ++j) {
            float2 s = st[j];
            float r = fmaxf((vv[j] - s.x) * s.y, 0.f);
            __bf16 hh = (__bf16)r;
            hi[j] = hh; lo[j] = (__bf16)(r - (float)hh);
        }
    }
    *(bf16x4*)(outH + o) = hi;
    *(bf16x4*)(outL + o) = lo;
}

// pooled NHWC [P][16][H][W][64] + stats + d -> XB padded hi/lo [C][16][Hp][Wp][64]
__global__ void mix_split(const float* __restrict__ pooled, const float2* __restrict__ stats,
                          const float* __restrict__ d,
                          __bf16* __restrict__ outH, __bf16* __restrict__ outL,
                          int H, int W, int P, long strideP, int total)
{
    int idx = blockIdx.x * 256 + threadIdx.x;
    if (idx >= total) return;
    const int Hp = H + 2, Wp = W + 2;
    int c4 = idx & 15;
    int t  = idx >> 4;
    int wp = t % Wp; t /= Wp;
    int hp = t % Hp; t /= Hp;
    int n  = t & 15;
    int cc = t >> 4;
    size_t o = (((size_t)(cc * 16 + n) * Hp + hp) * Wp + wp) * 64 + c4 * 4;
    bf16x4 hi, lo;
    if (hp == 0 || hp == Hp - 1 || wp == 0 || wp == Wp - 1) {
#pragma unroll
        for (int j = 0; j < 4; ++j) { hi[j] = (__bf16)0.f; lo[j] = (__bf16)0.f; }
    } else {
        float a[4] = {0.f, 0.f, 0.f, 0.f};
        const float* pb = pooled + (((size_t)n * H + (hp - 1)) * W + (wp - 1)) * 64 + c4 * 4;
        for (int p = 0; p < P; ++p) {
            float4 v = *(const float4*)(pb + (size_t)p * strideP);
            const float2* st = stats + p * 64 + c4 * 4;
            float dc = d[cc * P + p];
            float vv[4] = {v.x, v.y, v.z, v.w};
#pragma unroll
            for (int j = 0; j < 4; ++j) {
                float2 s = st[j];
                a[j] = fmaf(dc, fmaxf((vv[j] - s.x) * s.y, 0.f), a[j]);
            }
        }
#pragma unroll
        for (int j = 0; j < 4; ++j) {
            __bf16 hh = (__bf16)a[j];
            hi[j] = hh; lo[j] = (__bf16)(a[j] - (float)hh);
        }
    }
    *(bf16x4*)(outH + o) = hi;
    *(bf16x4*)(outL + o) = lo;
}

// L3 mix: pooled [16][16][7][7][32] -> XB3 fp32 [40][16][7][7][32]
__global__ void mix_last(const float* __restrict__ pooled, const float2* __restrict__ stats,
                         const float* __restrict__ d, float* __restrict__ out, int total)
{
    int idx = blockIdx.x * 256 + threadIdx.x;
    if (idx >= total) return;
    int c  = idx & 31;
    int t  = idx >> 5;
    int hw = t % 49; t /= 49;
    int n  = t & 15;
    int a  = t >> 4;
    float acc = 0.f;
    const float* pb = pooled + ((size_t)n * 49 + hw) * 32 + c;
    for (int p = 0; p < 16; ++p) {
        float2 s = stats[p * 64 + c];
        acc = fmaf(d[a * 16 + p], fmaxf((pb[(size_t)p * 25088] - s.x) * s.y, 0.f), acc);
    }
    out[idx] = acc;
}

// x NCHW [16][3][256][256] -> packed NHWC4 hi/lo [16][256][256][4]
__global__ void prep_x(const float* __restrict__ x, __bf16* __restrict__ xH,
                       __bf16* __restrict__ xL)
{
    int idx = blockIdx.x * 256 + threadIdx.x;   // 16*65536
    if (idx >= 16 * 65536) return;
    int n = idx >> 16, hw = idx & 65535;
    bf16x4 hi, lo;
#pragma unroll
    for (int ci = 0; ci < 3; ++ci) {
        float v = x[((size_t)n * 3 + ci) * 65536 + hw];
        __bf16 hh = (__bf16)v;
        hi[ci] = hh; lo[ci] = (__bf16)(v - (float)hh);
    }
    hi[3] = (__bf16)0.f; lo[3] = (__bf16)0.f;
    *(bf16x4*)(xH + (size_t)idx * 4) = hi;
    *(bf16x4*)(xL + (size_t)idx * 4) = lo;
}

// conv1 weights [64][3][7][7] -> hi/lo panels [28 kblk][64][8], k=kh*32+kw*4+ci
__global__ void wtrans1(const float* __restrict__ w, __bf16* __restrict__ wH,
                        __bf16* __restrict__ wL)
{
    int i = blockIdx.x * 256 + threadIdx.x;
    if (i >= 28 * 512) return;
    int j = i & 7, n = (i >> 3) & 63, kb = i >> 9;
    int k = kb * 8 + j;
    int kh = k >> 5, r = k & 31, kw = r >> 2, ci = r & 3;
    float v = (kw < 7 && ci < 3) ? w[((n * 3 + ci) * 7 + kh) * 7 + kw] : 0.f;
    __bf16 hh = (__bf16)v;
    wH[i] = hh; wL[i] = (__bf16)(v - (float)hh);
}

// 3x3 weights [P][Cout][64][3][3] -> hi/lo panels [p][72 kblk][64][8],
// k = (kh*3+kw)*64 + ci
__global__ void wtrans3(const float* __restrict__ w, __bf16* __restrict__ wH,
                        __bf16* __restrict__ wL, int P, int Cout)
{
    int total = P * 72 * 512;
    for (int i = blockIdx.x * 256 + threadIdx.x; i < total; i += gridDim.x * 256) {
        int j = i & 7, n = (i >> 3) & 63, kb = (i >> 9) % 72, p = (i >> 9) / 72;
        int k = kb * 8 + j;
        int ci = k & 63, tap = k >> 6, kh = tap / 3, kw = tap - 3 * kh;
        float v = (n < Cout) ? w[(((size_t)(p * Cout + n)) * 64 + ci) * 9 + kh * 3 + kw] : 0.f;
        __bf16 hh = (__bf16)v;
        wH[i] = hh; wL[i] = (__bf16)(v - (float)hh);
    }
}

// d = softmax_p( log(softmax_p(br*2)) / t ) for all 4 layers
__global__ void dcalc(const float* __restrict__ br0, const float* __restrict__ br1,
                      const float* __restrict__ br2, const float* __restrict__ br3,
                      const void* __restrict__ tptr, float* __restrict__ D)
{
    const int L = blockIdx.x;
    const float* br; int C, P, off;
    if      (L == 0) { br = br0; C = 4;  P = 2;  off = 0;   }
    else if (L == 1) { br = br1; C = 8;  P = 4;  off = 8;   }
    else if (L == 2) { br = br2; C = 16; P = 8;  off = 40;  }
    else             { br = br3; C = 40; P = 16; off = 168; }
    int ti = *(const int*)tptr;
    float t = (ti > 0 && ti < 1000000) ? (float)ti : *(const float*)tptr;
    const int c = threadIdx.x;
    if (c >= C) return;
    float u[16];
    float mx = -1e30f;
#pragma unroll
    for (int p = 0; p < 16; ++p) if (p < P) { u[p] = br[c * P + p] * 2.0f; mx = fmaxf(mx, u[p]); }
    float se = 0.f;
#pragma unroll
    for (int p = 0; p < 16; ++p) if (p < P) se += expf(u[p] - mx);
    float lse = mx + logf(se);
    float mx2 = -1e30f;
#pragma unroll
    for (int p = 0; p < 16; ++p) if (p < P) { u[p] = (u[p] - lse) / t; mx2 = fmaxf(mx2, u[p]); }
    float se2 = 0.f;
#pragma unroll
    for (int p = 0; p < 16; ++p) if (p < P) { u[p] = expf(u[p] - mx2); se2 += u[p]; }
#pragma unroll
    for (int p = 0; p < 16; ++p) if (p < P) D[off + c * P + p] = u[p] / se2;
}

// h1[a,b,i] = relu( sum_f f[a,b,f]*fw1[a,f,i] + fb1[a,i] ); f stored (h,w,c),
// fw1 indexed (c,h,w)
__global__ __launch_bounds__(128) void fc1_k(const float* __restrict__ f,
                                             const float* __restrict__ w1,
                                             const float* __restrict__ b1,
                                             float* __restrict__ h1)
{
    const int a = blockIdx.x >> 4;
    const int b = blockIdx.x & 15;
    const int i = threadIdx.x;
    const float* fv = f + ((size_t)a * 16 + b) * 1568;
    const float* wv = w1 + (size_t)a * 1568 * 128 + i;
    float acc = b1[a * 128 + i];
    for (int hw = 0; hw < 49; ++hw)
        for (int c = 0; c < 32; ++c)
            acc = fmaf(fv[hw * 32 + c], wv[(size_t)(c * 49 + hw) * 128], acc);
    h1[((size_t)a * 16 + b) * 128 + i] = fmaxf(acc, 0.f);
}

__global__ __launch_bounds__(128) void fc23_k(const float* __restrict__ h1,
                                              const float* __restrict__ w2,
                                              const float* __restrict__ b2,
                                              const float* __restrict__ w3,
                                              const float* __restrict__ b3,
                                              float* __restrict__ out)
{
    __shared__ float sh1[16][128];
    __shared__ float sh2[16][128];
    const int a = blockIdx.x;
    const int i = threadIdx.x;
    for (int b = 0; b < 16; ++b) sh1[b][i] = h1[((size_t)a * 16 + b) * 128 + i];
    __syncthreads();
    float acc[16];
#pragma unroll
    for (int b = 0; b < 16; ++b) acc[b] = b2[a * 128 + i];
    for (int ff = 0; ff < 128; ++ff) {
        float wv = w2[((size_t)a * 128 + ff) * 128 + i];
#pragma unroll
        for (int b = 0; b < 16; ++b) acc[b] = fmaf(sh1[b][ff], wv, acc[b]);
    }
    for (int b = 0; b < 16; ++b) sh2[b][i] = fmaxf(acc[b], 0.f);
    __syncthreads();
    if (i < 16) {
        float o = b3[a];
        for (int ff = 0; ff < 128; ++ff) o = fmaf(sh2[i][ff], w3[a * 128 + ff], o);
        out[i * 40 + a] = o;
    }
}

extern "C" void kernel_launch(void* const* d_in, const int* in_sizes, int n_in,
                              void* d_out, int out_size, void* d_ws, size_t ws_size,
                              hipStream_t stream)
{
    (void)in_sizes; (void)n_in;

    const float* x   = (const float*)d_in[0];
    const float* w10 = (const float*)d_in[1];
    const float* wa[4] = {(const float*)d_in[3],  (const float*)d_in[7],
                          (const float*)d_in[11], (const float*)d_in[15]};
    const float* wb[4] = {(const float*)d_in[5],  (const float*)d_in[9],
                          (const float*)d_in[13], (const float*)d_in[17]};
    const float* br[4] = {(const float*)d_in[19], (const float*)d_in[20],
                          (const float*)d_in[21], (const float*)d_in[22]};
    const float* fw1 = (const float*)d_in[23];
    const float* fb1 = (const float*)d_in[24];
    const float* fw2 = (const float*)d_in[25];
    const float* fb2 = (const float*)d_in[26];
    const float* fw3 = (const float*)d_in[27];
    const float* fb3 = (const float*)d_in[28];
    float* out = (float*)d_out;

    const int Pl[4]  = {2, 4, 8, 16};
    const int CBs[4] = {64, 64, 64, 32};

    // ---- workspace arenas (f32 units); total 60,264,704 f32 = 241.06 MB ----
    const size_t NEED = 60264704ull * 4ull;
    if (ws_size < NEED) {
        hipMemsetAsync(d_out, 0, (size_t)out_size * sizeof(float), stream);
        return;
    }
    float* ws = (float*)d_ws;
    size_t o = 0;
    __bf16* WT1H = (__bf16*)(ws + o); o += 7168;   // 14336 bf16
    __bf16* WT1L = (__bf16*)(ws + o); o += 7168;
    __bf16 *WTAH[4], *WTAL[4], *WTBH[4], *WTBL[4];
    for (int L = 0; L < 4; ++L) {                  // P*72*512 bf16 each
        WTAH[L] = (__bf16*)(ws + o); o += (size_t)Pl[L] * 18432;
        WTAL[L] = (__bf16*)(ws + o); o += (size_t)Pl[L] * 18432;
        WTBH[L] = (__bf16*)(ws + o); o += (size_t)Pl[L] * 18432;
        WTBL[L] = (__bf16*)(ws + o); o += (size_t)Pl[L] * 18432;
    }
    float*  D     = ws + o; o += 1024;
    float2* STATS = (float2*)(ws + o); o += 4352;
    float2* STATS_C1 = STATS;
    float2* STATS_A  = STATS + 64;
    float2* STATS_B  = STATS + 1088;
    float*  H1 = ws + o; o += 81920;
    float*  A6 = ws + o; o += 524288;      // small conv partials
    float*  A5 = ws + o; o += 7872512;     // pooled raw / conv1 partials
    float*  A4 = ws + o; o += 16000000;    // raw conv outputs (fp32 NHWC)
    float*  A3 = ws + o; o += 16777216;    // split bufs (hi/lo bf16) / xc
    float*  A2 = ws + o; o += 16777216;    // Y / XB chain

    float2* PART   = (float2*)A6;
    float2* PARTC1 = (float2*)A5;
    __bf16* xcH = (__bf16*)A3;
    __bf16* xcL = (__bf16*)(A3 + 2097152);
    __bf16* A2H = (__bf16*)A2;             // hi at A2[0:], lo after
    __bf16* A2L = (__bf16*)(A2 + 8388608);
    __bf16* A3H = (__bf16*)A3;
    __bf16* A3L = (__bf16*)(A3 + 8388608);

    // ---- weights + mix coefficients + conv1 input prep ----
    prep_x<<<4096, 256, 0, stream>>>(x, xcH, xcL);
    wtrans1<<<56, 256, 0, stream>>>(w10, WT1H, WT1L);
    for (int L = 0; L < 4; ++L) {
        int tA = Pl[L] * 72 * 512;
        wtrans3<<<DIVUP(tA, 256), 256, 0, stream>>>(wa[L], WTAH[L], WTAL[L], Pl[L], 64);
        wtrans3<<<DIVUP(tA, 256), 256, 0, stream>>>(wb[L], WTBH[L], WTBL[L], Pl[L], CBs[L]);
    }
    dcalc<<<4, 64, 0, stream>>>(br[0], br[1], br[2], br[3], d_in[29], D);

    // ---- conv1: xc -> pooled raw A4 [16,125,125,64] + stats ----
    conv_mfma<1, 1><<<dim3(7813, 1, 1), 256, 0, stream>>>(
        xcH, xcL, 0, WT1H, WT1L, A4, 0, PARTC1,
        256, 256, 250, 250, 64, 1000000, 7, 125, 125, 125, 125);
    bn_finalize<<<64, 256, 0, stream>>>(PARTC1, 7813, 1.0 / 1000000.0, STATS_C1);
    // Y = bn_split(A4) -> A2 padded [16][127][127][64]
    bn_split<<<DIVUP(16 * 127 * 127 * 16, 256), 256, 0, stream>>>(
        A4, STATS_C1, A2H, A2L, 125, 125, 16 * 127 * 127 * 16);

    // ---- layer 0 (per parent; Y shared) ----
    for (int p = 0; p < 2; ++p) {
        conv_mfma<0, 0><<<dim3(1954, 1, 1), 256, 0, stream>>>(
            A2H, A2L, 0, WTAH[0] + (size_t)p * 36864, WTAL[0] + (size_t)p * 36864,
            A4, 0, PART, 127, 127, 125, 125, 64, 250000, 18, 0, 0, 1, 1);
        bn_finalize<<<64, 256, 0, stream>>>(PART, 1954, 1.0 / 250000.0, STATS_A);
        bn_split<<<DIVUP(16 * 127 * 127 * 16, 256), 256, 0, stream>>>(
            A4, STATS_A, A3H, A3L, 125, 125, 16 * 127 * 127 * 16);
        conv_mfma<1, 0><<<dim3(1985, 1, 1), 256, 0, stream>>>(
            A3H, A3L, 0, WTBH[0] + (size_t)p * 36864, WTBL[0] + (size_t)p * 36864,
            A5 + (size_t)p * 3936256, 0, PART,
            127, 127, 125, 125, 64, 254016, 18, 62, 62, 63, 63);
        bn_finalize<<<64, 256, 0, stream>>>(PART, 1985, 1.0 / 250000.0, STATS_B + p * 64);
    }
    mix_split<<<DIVUP(4 * 16 * 64 * 64 * 16, 256), 256, 0, stream>>>(
        A5, STATS_B, D + 0, A2H, A2L, 62, 62, 2, 3936256, 4 * 16 * 64 * 64 * 16);

    // ---- layer 1 (z=4) ----
    conv_mfma<0, 0><<<dim3(481, 1, 4), 256, 0, stream>>>(
        A2H, A2L, 4194304, WTAH[1], WTAL[1], A4, 3936256, PART,
        64, 64, 62, 62, 64, 61504, 18, 0, 0, 1, 1);
    bn_finalize<<<256, 256, 0, stream>>>(PART, 481, 1.0 / 61504.0, STATS_A);
    bn_split<<<DIVUP(64 * 64 * 64 * 16, 256), 256, 0, stream>>>(
        A4, STATS_A, A3H, A3L, 62, 62, 64 * 64 * 64 * 16);
    conv_mfma<1, 0><<<dim3(481, 1, 4), 256, 0, stream>>>(
        A3H, A3L, 4194304, WTBH[1], WTBL[1], A5, 984064, PART,
        64, 64, 62, 62, 64, 61504, 18, 31, 31, 31, 31);
    bn_finalize<<<256, 256, 0, stream>>>(PART, 481, 1.0 / 61504.0, STATS_B);
    mix_split<<<DIVUP(8 * 16 * 33 * 33 * 16, 256), 256, 0, stream>>>(
        A5, STATS_B, D + 8, A2H, A2L, 31, 31, 4, 984064, 8 * 16 * 33 * 33 * 16);

    // ---- layer 2 (z=8) ----
    conv_mfma<0, 0><<<dim3(121, 1, 8), 256, 0, stream>>>(
        A2H, A2L, 1115136, WTAH[2], WTAL[2], A4, 984064, PART,
        33, 33, 31, 31, 64, 15376, 18, 0, 0, 1, 1);
    bn_finalize<<<512, 256, 0, stream>>>(PART, 121, 1.0 / 15376.0, STATS_A);
    bn_split<<<DIVUP(128 * 33 * 33 * 16, 256), 256, 0, stream>>>(
        A4, STATS_A, A3H, A3L, 31, 31, 128 * 33 * 33 * 16);
    conv_mfma<1, 0><<<dim3(128, 1, 8), 256, 0, stream>>>(
        A3H, A3L, 1115136, WTBH[2], WTBL[2], A5, 230400, PART,
        33, 33, 31, 31, 64, 16384, 18, 15, 15, 16, 16);
    bn_finalize<<<512, 256, 0, stream>>>(PART, 128, 1.0 / 15376.0, STATS_B);
    mix_split<<<DIVUP(16 * 16 * 17 * 17 * 16, 256), 256, 0, stream>>>(
        A5, STATS_B, D + 40, A2H, A2L, 15, 15, 8, 230400, 16 * 16 * 17 * 17 * 16);

    // ---- layer 3 (z=16) ----
    conv_mfma<0, 0><<<dim3(29, 1, 16), 256, 0, stream>>>(
        A2H, A2L, 295936, WTAH[3], WTAL[3], A4, 230400, PART,
        17, 17, 15, 15, 64, 3600, 18, 0, 0, 1, 1);
    bn_finalize<<<1024, 256, 0, stream>>>(PART, 29, 1.0 / 3600.0, STATS_A);
    bn_split<<<DIVUP(256 * 17 * 17 * 16, 256), 256, 0, stream>>>(
        A4, STATS_A, A3H, A3L, 15, 15, 256 * 17 * 17 * 16);
    conv_mfma<1, 0><<<dim3(32, 1, 16), 256, 0, stream>>>(
        A3H, A3L, 295936, WTBH[3], WTBL[3], A5, 25088, PART,
        17, 17, 15, 15, 32, 4096, 18, 7, 7, 8, 8);
    bn_finalize<<<1024, 256, 0, stream>>>(PART, 32, 1.0 / 3600.0, STATS_B);
    mix_last<<<DIVUP(40 * 16 * 49 * 32, 256), 256, 0, stream>>>(
        A5, STATS_B, D + 168, A2, 40 * 16 * 49 * 32);

    // ---- FC heads ----
    fc1_k<<<640, 128, 0, stream>>>(A2, fw1, fb1, H1);
    fc23_k<<<40, 128, 0, stream>>>(H1, fw2, fb2, fw3, fb3, out);
}

// Round 12
// 1160.238 us; speedup vs baseline: 1.1508x; 1.0100x over previous
//
#include <hip/hip_runtime.h>
#include <math.h>

#define DIVUP(a,b) (((a)+(b)-1)/(b))

typedef __bf16 bf16x8 __attribute__((ext_vector_type(8)));
typedef __bf16 bf16x4 __attribute__((ext_vector_type(4)));
typedef float  f32x4  __attribute__((ext_vector_type(4)));

// ---------------------------------------------------------------------------
// Implicit-GEMM conv, NHWC, split-bf16 3-MFMA. BM=128, BN=64, BK=32.
// 256 thr = 4 waves; wave wv owns rows [128bx+32wv,+32); 24 MFMA/wave/K-step.
// A:   direct global->VGPR in frag layout, double-buffered in named reg sets,
//      UNCONDITIONAL loads (invalid rows clamp to base 0; garbage C rows are
//      masked at the stats emit and by C-write guards).
// B-H: staged to LDS [64][40], double-buffered, ONE barrier per K-step.
// B-L: direct global->VGPR per K-step (panel is L1/L2-resident, shared).
// LDS per thread-K-step: 1 write + 4 reads (was 2+8) -> LDS pipe ~balanced
// with MFMA. XCD-aware bijective block swizzle (m204). POOL=1: quad-M +
// fused 2x2 maxpool. Emits per-block per-channel (sum,sumsq) partials.
// ---------------------------------------------------------------------------
template<int POOL, int C1>
__global__ __launch_bounds__(256, 4) void conv_mfma(
    const __bf16* __restrict__ inH, const __bf16* __restrict__ inL, long inZstride,
    const __bf16* __restrict__ wtH, const __bf16* __restrict__ wtL,
    float* __restrict__ out, long outZstride, float2* __restrict__ part,
    int HinP, int WinP, int Hout, int Wout, int Cout, int M, int niter,
    int H2, int W2, int H2c, int W2c)
{
    __shared__ __align__(16) char smem[10240];   // B-H dbuf: 2 x 5120
    __shared__ __align__(16) float2 red[64 * 17];

    // ---- bijective XCD swizzle (m204) ----
    int bx;
    {
        int n = gridDim.x, orig = blockIdx.x;
        int q = n >> 3, r = n & 7;
        int xcd = orig & 7, idx = orig >> 3;
        bx = (xcd < r ? xcd * (q + 1) : r * (q + 1) + (xcd - r) * q) + idx;
    }

    const int tid  = threadIdx.x;
    const int wv   = tid >> 6;
    const int ln15 = tid & 15;
    const int lhi  = (tid >> 4) & 3;
    const int sn   = tid & 63;        // B-H stage: n row this thread stages
    const int skb  = tid >> 6;        // B-H stage: kb slot
    const int sdst = sn * 40 + skb * 8;

    const __bf16* ipH = inH + (size_t)blockIdx.z * inZstride;
    const __bf16* ipL = inL + (size_t)blockIdx.z * inZstride;

    // clamped base for pixel row m (invalid rows -> base 0, valid memory)
    auto pixbase = [&](int mA) -> int {
        int nb, h, w; bool valid;
        if (POOL) {
            int r = mA & 3, quad = mA >> 2;
            int cpi = H2c * W2c;
            nb = quad / cpi;
            int rem = quad - nb * cpi;
            int h2 = rem / W2c, w2 = rem - h2 * W2c;
            h = h2 * 2 + (r >> 1); w = w2 * 2 + (r & 1);
            valid = (mA < M) && (h < Hout) && (w < Wout);
        } else {
            int HW = Hout * Wout;
            valid = mA < M;
            int mm = valid ? mA : 0;
            nb = mm / HW;
            int rem = mm - nb * HW;
            h = rem / Wout; w = rem - h * Wout;
        }
        if (!valid) { nb = 0; h = 0; w = 0; }
        if (C1) return ((nb * 256 + h) * 256 + w) * 4;
        return ((nb * HinP + h) * WinP + w) * 64;
    };
    auto rowvalid = [&](int mA) -> bool {
        if (POOL) {
            int r = mA & 3, quad = mA >> 2;
            int cpi = H2c * W2c;
            int nb = quad / cpi;
            int rem = quad - nb * cpi;
            int h2 = rem / W2c, w2 = rem - h2 * W2c;
            int h = h2 * 2 + (r >> 1), w = w2 * 2 + (r & 1);
            return (mA < M) && (h < Hout) && (w < Wout);
        }
        return mA < M;
    };

    int abase[2];
#pragma unroll
    for (int q = 0; q < 2; ++q)
        abase[q] = pixbase(bx * 128 + wv * 32 + q * 16 + ln15);

    // 8-bit validity mask for this thread's C rows (stats masking)
    unsigned vmask = 0;
#pragma unroll
    for (int q = 0; q < 2; ++q)
#pragma unroll
        for (int r = 0; r < 4; ++r)
            vmask |= (unsigned)rowvalid(bx * 128 + wv * 32 + q * 16 + lhi * 4 + r)
                     << (q * 4 + r);

    const __bf16* wpH = wtH + (size_t)blockIdx.z * niter * 2048;
    const __bf16* wpL = wtL + (size_t)blockIdx.z * niter * 2048;

    auto loadA = [&](int it, bf16x8 (&aH)[2], bf16x8 (&aL)[2]) {
        int off;
        if (C1) off = it * 1024 + lhi * 8;
        else { int tap = it >> 1; int kh = tap / 3, kw = tap - 3 * kh;
               off = (kh * WinP + kw) * 64 + (it & 1) * 32 + lhi * 8; }
#pragma unroll
        for (int q = 0; q < 2; ++q) {
            aH[q] = *(const bf16x8*)(ipH + abase[q] + off);
            aL[q] = *(const bf16x8*)(ipL + abase[q] + off);
        }
    };

    f32x4 acc[2][4] = {};
    bf16x8 a0H[2], a0L[2], a1H[2], a1L[2];
    bf16x8 sbH;

    // ---- prologue: buf0 <- B-H(0); a0 <- A(0); a1 <- A(1); sbH <- B-H(1) ----
    {
        size_t a = (size_t)(skb * 64 + sn) * 8;
        bf16x8 h = *(const bf16x8*)(wpH + a);
        *(bf16x8*)((__bf16*)smem + sdst) = h;
        loadA(0, a0H, a0L);
        if (niter > 1) {
            loadA(1, a1H, a1L);
            sbH = *(const bf16x8*)(wpH + (size_t)((4 + skb) * 64 + sn) * 8);
        }
        __syncthreads();
    }

#define REGION(IT, CUR, AH, AL)                                                   \
    {                                                                             \
        const int itc = (IT);                                                     \
        if (itc + 1 < niter)                                                      \
            *(bf16x8*)((__bf16*)(smem + ((CUR) ^ 1) * 5120) + sdst) = sbH;        \
        bf16x8 bLf[4];                                                            \
        _Pragma("unroll")                                                         \
        for (int t = 0; t < 4; ++t)                                               \
            bLf[t] = *(const bf16x8*)(wpL +                                       \
                         (size_t)((itc * 4 + lhi) * 64 + t * 16 + ln15) * 8);     \
        const __bf16* rb = (const __bf16*)(smem + (CUR) * 5120);                  \
        bf16x8 bHf[4];                                                            \
        _Pragma("unroll")                                                         \
        for (int t = 0; t < 4; ++t)                                               \
            bHf[t] = *(const bf16x8*)(rb + (t * 16 + ln15) * 40 + lhi * 8);       \
        if (itc + 2 < niter)                                                      \
            sbH = *(const bf16x8*)(wpH +                                          \
                      (size_t)(((itc + 2) * 4 + skb) * 64 + sn) * 8);             \
        _Pragma("unroll")                                                         \
        for (int t = 0; t < 4; ++t)                                               \
            _Pragma("unroll")                                                     \
            for (int q = 0; q < 2; ++q)                                           \
                acc[q][t] = __builtin_amdgcn_mfma_f32_16x16x32_bf16(AH[q], bHf[t], acc[q][t], 0, 0, 0); \
        _Pragma("unroll")                                                         \
        for (int t = 0; t < 4; ++t)                                               \
            _Pragma("unroll")                                                     \
            for (int q = 0; q < 2; ++q)                                           \
                acc[q][t] = __builtin_amdgcn_mfma_f32_16x16x32_bf16(AL[q], bHf[t], acc[q][t], 0, 0, 0); \
        _Pragma("unroll")                                                         \
        for (int t = 0; t < 4; ++t)                                               \
            _Pragma("unroll")                                                     \
            for (int q = 0; q < 2; ++q)                                           \
                acc[q][t] = __builtin_amdgcn_mfma_f32_16x16x32_bf16(AH[q], bLf[t], acc[q][t], 0, 0, 0); \
        if (itc + 2 < niter) loadA(itc + 2, AH, AL);                              \
        __syncthreads();                                                          \
    }

    for (int it = 0; it < niter; it += 2) {
        REGION(it, 0, a0H, a0L);
        if (it + 1 < niter) REGION(it + 1, 1, a1H, a1L);
    }
#undef REGION

    // ---- per-block per-channel (sum,sumsq) partials (masked rows) ----
#pragma unroll
    for (int t = 0; t < 4; ++t) {
        float s = 0.f, s2 = 0.f;
#pragma unroll
        for (int q = 0; q < 2; ++q)
#pragma unroll
            for (int r = 0; r < 4; ++r) {
                float v = ((vmask >> (q * 4 + r)) & 1u) ? acc[q][t][r] : 0.f;
                s += v; s2 += v * v;
            }
        red[(ln15 + 16 * t) * 17 + (wv * 4 + lhi)] = make_float2(s, s2);
    }
    __syncthreads();
    if (tid < 64) {
        float s = 0.f, s2 = 0.f;
#pragma unroll
        for (int q = 0; q < 16; ++q) { float2 v = red[tid * 17 + q]; s += v.x; s2 += v.y; }
        part[((size_t)blockIdx.z * 64 + tid) * gridDim.x + bx] = make_float2(s, s2);
    }

    // ---- NHWC output ----
    float* zout = out + (size_t)blockIdx.z * outZstride;
#pragma unroll
    for (int q = 0; q < 2; ++q) {
        const int mbase = bx * 128 + wv * 32 + q * 16 + lhi * 4;
        if (POOL) {
            if (mbase < M) {
                int quad = mbase >> 2;
                int cpi  = H2c * W2c;
                int nb2  = quad / cpi;
                int rem  = quad - nb2 * cpi;
                int h2 = rem / W2c, w2 = rem - h2 * W2c;
                if (h2 < H2 && w2 < W2) {
                    float* op = zout + ((size_t)(nb2 * H2 + h2) * W2 + w2) * Cout;
#pragma unroll
                    for (int t = 0; t < 4; ++t) {
                        int n = ln15 + 16 * t;
                        if (n < Cout) {
                            float mx = fmaxf(fmaxf(acc[q][t][0], acc[q][t][1]),
                                             fmaxf(acc[q][t][2], acc[q][t][3]));
                            op[n] = mx;
                        }
                    }
                }
            }
        } else {
#pragma unroll
            for (int r = 0; r < 4; ++r) {
                int m = mbase + r;
                if (m < M) {
                    float* op = zout + (size_t)m * Cout;
#pragma unroll
                    for (int t = 0; t < 4; ++t) {
                        int n = ln15 + 16 * t;
                        if (n < Cout) op[n] = acc[q][t][r];
                    }
                }
            }
        }
    }
}

// partials -> (mean, rsqrt(var+eps)) per (z,channel)
__global__ __launch_bounds__(256) void bn_finalize(const float2* __restrict__ part,
                                                   int nblkx, double Ninv,
                                                   float2* __restrict__ stats)
{
    __shared__ double sh[512];
    const int zc = blockIdx.x, tid = threadIdx.x;
    const float2* p = part + (size_t)zc * nblkx;
    double s = 0, s2 = 0;
    for (int i = tid; i < nblkx; i += 256) { s += p[i].x; s2 += p[i].y; }
    sh[tid] = s; sh[256 + tid] = s2;
    __syncthreads();
    for (int st = 128; st > 0; st >>= 1) {
        if (tid < st) { sh[tid] += sh[tid + st]; sh[256 + tid] += sh[256 + tid + st]; }
        __syncthreads();
    }
    if (tid == 0) {
        float mean = (float)(sh[0] * Ninv);
        float var  = (float)(sh[256] * Ninv - (double)mean * (double)mean);
        if (var < 0.f) var = 0.f;
        stats[zc] = make_float2(mean, rsqrtf(var + 1e-5f));
    }
}

// raw NHWC fp32 + stats -> padded NHWC bf16 hi/lo with zero border.
__global__ void bn_split(const float* __restrict__ raw, const float2* __restrict__ stats,
                         __bf16* __restrict__ outH, __bf16* __restrict__ outL,
                         int H, int W, int total)
{
    int idx = blockIdx.x * 256 + threadIdx.x;
    if (idx >= total) return;
    const int Hp = H + 2, Wp = W + 2;
    int c4 = idx & 15;
    int t  = idx >> 4;
    int wp = t % Wp; t /= Wp;
    int hp = t % Hp; int img = t / Hp;
    size_t o = (((size_t)img * Hp + hp) * Wp + wp) * 64 + c4 * 4;
    bf16x4 hi, lo;
    if (hp == 0 || hp == Hp - 1 || wp == 0 || wp == Wp - 1) {
#pragma unroll
        for (int j = 0; j < 4; ++j) { hi[j] = (__bf16)0.f; lo[j] = (__bf16)0.f; }
    } else {
        float4 v = *(const float4*)(raw + (((size_t)img * H + (hp - 1)) * W + (wp - 1)) * 64 + c4 * 4);
        const float2* st = stats + (img >> 4) * 64 + c4 * 4;
        float vv[4] = {v.x, v.y, v.z, v.w};
#pragma unroll
        for (int j = 0; j < 4; ++j) {
            float2 s = st[j];
            float r = fmaxf((vv[j] - s.x) * s.y, 0.f);
            __bf16 hh = (__bf16)r;
            hi[j] = hh; lo[j] = (__bf16)(r - (float)hh);
        }
    }
    *(bf16x4*)(outH + o) = hi;
    *(bf16x4*)(outL + o) = lo;
}

// pooled NHWC [P][16][H][W][64] + stats + d -> XB padded hi/lo [C][16][Hp][Wp][64]
__global__ void mix_split(const float* __restrict__ pooled, const float2* __restrict__ stats,
                          const float* __restrict__ d,
                          __bf16* __restrict__ outH, __bf16* __restrict__ outL,
                          int H, int W, int P, long strideP, int total)
{
    int idx = blockIdx.x * 256 + threadIdx.x;
    if (idx >= total) return;
    const int Hp = H + 2, Wp = W + 2;
    int c4 = idx & 15;
    int t  = idx >> 4;
    int wp = t % Wp; t /= Wp;
    int hp = t % Hp; t /= Hp;
    int n  = t & 15;
    int cc = t >> 4;
    size_t o = (((size_t)(cc * 16 + n) * Hp + hp) * Wp + wp) * 64 + c4 * 4;
    bf16x4 hi, lo;
    if (hp == 0 || hp == Hp - 1 || wp == 0 || wp == Wp - 1) {
#pragma unroll
        for (int j = 0; j < 4; ++j) { hi[j] = (__bf16)0.f; lo[j] = (__bf16)0.f; }
    } else {
        float a[4] = {0.f, 0.f, 0.f, 0.f};
        const float* pb = pooled + (((size_t)n * H + (hp - 1)) * W + (wp - 1)) * 64 + c4 * 4;
        for (int p = 0; p < P; ++p) {
            float4 v = *(const float4*)(pb + (size_t)p * strideP);
            const float2* st = stats + p * 64 + c4 * 4;
            float dc = d[cc * P + p];
            float vv[4] = {v.x, v.y, v.z, v.w};
#pragma unroll
            for (int j = 0; j < 4; ++j) {
                float2 s = st[j];
                a[j] = fmaf(dc, fmaxf((vv[j] - s.x) * s.y, 0.f), a[j]);
            }
        }
#pragma unroll
        for (int j = 0; j < 4; ++j) {
            __bf16 hh = (__bf16)a[j];
            hi[j] = hh; lo[j] = (__bf16)(a[j] - (float)hh);
        }
    }
    *(bf16x4*)(outH + o) = hi;
    *(bf16x4*)(outL + o) = lo;
}

// L3 mix: pooled [16][16][7][7][32] -> XB3 fp32 [40][16][7][7][32]
__global__ void mix_last(const float* __restrict__ pooled, const float2* __restrict__ stats,
                         const float* __restrict__ d, float* __restrict__ out, int total)
{
    int idx = blockIdx.x * 256 + threadIdx.x;
    if (idx >= total) return;
    int c  = idx & 31;
    int t  = idx >> 5;
    int hw = t % 49; t /= 49;
    int n  = t & 15;
    int a  = t >> 4;
    float acc = 0.f;
    const float* pb = pooled + ((size_t)n * 49 + hw) * 32 + c;
    for (int p = 0; p < 16; ++p) {
        float2 s = stats[p * 64 + c];
        acc = fmaf(d[a * 16 + p], fmaxf((pb[(size_t)p * 25088] - s.x) * s.y, 0.f), acc);
    }
    out[idx] = acc;
}

// x NCHW [16][3][256][256] -> packed NHWC4 hi/lo [16][256][256][4]
__global__ void prep_x(const float* __restrict__ x, __bf16* __restrict__ xH,
                       __bf16* __restrict__ xL)
{
    int idx = blockIdx.x * 256 + threadIdx.x;   // 16*65536
    if (idx >= 16 * 65536) return;
    int n = idx >> 16, hw = idx & 65535;
    bf16x4 hi, lo;
#pragma unroll
    for (int ci = 0; ci < 3; ++ci) {
        float v = x[((size_t)n * 3 + ci) * 65536 + hw];
        __bf16 hh = (__bf16)v;
        hi[ci] = hh; lo[ci] = (__bf16)(v - (float)hh);
    }
    hi[3] = (__bf16)0.f; lo[3] = (__bf16)0.f;
    *(bf16x4*)(xH + (size_t)idx * 4) = hi;
    *(bf16x4*)(xL + (size_t)idx * 4) = lo;
}

// conv1 weights [64][3][7][7] -> hi/lo panels [28 kblk][64][8], k=kh*32+kw*4+ci
__global__ void wtrans1(const float* __restrict__ w, __bf16* __restrict__ wH,
                        __bf16* __restrict__ wL)
{
    int i = blockIdx.x * 256 + threadIdx.x;
    if (i >= 28 * 512) return;
    int j = i & 7, n = (i >> 3) & 63, kb = i >> 9;
    int k = kb * 8 + j;
    int kh = k >> 5, r = k & 31, kw = r >> 2, ci = r & 3;
    float v = (kw < 7 && ci < 3) ? w[((n * 3 + ci) * 7 + kh) * 7 + kw] : 0.f;
    __bf16 hh = (__bf16)v;
    wH[i] = hh; wL[i] = (__bf16)(v - (float)hh);
}

// 3x3 weights [P][Cout][64][3][3] -> hi/lo panels [p][72 kblk][64][8],
// k = (kh*3+kw)*64 + ci
__global__ void wtrans3(const float* __restrict__ w, __bf16* __restrict__ wH,
                        __bf16* __restrict__ wL, int P, int Cout)
{
    int total = P * 72 * 512;
    for (int i = blockIdx.x * 256 + threadIdx.x; i < total; i += gridDim.x * 256) {
        int j = i & 7, n = (i >> 3) & 63, kb = (i >> 9) % 72, p = (i >> 9) / 72;
        int k = kb * 8 + j;
        int ci = k & 63, tap = k >> 6, kh = tap / 3, kw = tap - 3 * kh;
        float v = (n < Cout) ? w[(((size_t)(p * Cout + n)) * 64 + ci) * 9 + kh * 3 + kw] : 0.f;
        __bf16 hh = (__bf16)v;
        wH[i] = hh; wL[i] = (__bf16)(v - (float)hh);
    }
}

// d = softmax_p( log(softmax_p(br*2)) / t ) for all 4 layers
__global__ void dcalc(const float* __restrict__ br0, const float* __restrict__ br1,
                      const float* __restrict__ br2, const float* __restrict__ br3,
                      const void* __restrict__ tptr, float* __restrict__ D)
{
    const int L = blockIdx.x;
    const float* br; int C, P, off;
    if      (L == 0) { br = br0; C = 4;  P = 2;  off = 0;   }
    else if (L == 1) { br = br1; C = 8;  P = 4;  off = 8;   }
    else if (L == 2) { br = br2; C = 16; P = 8;  off = 40;  }
    else             { br = br3; C = 40; P = 16; off = 168; }
    int ti = *(const int*)tptr;
    float t = (ti > 0 && ti < 1000000) ? (float)ti : *(const float*)tptr;
    const int c = threadIdx.x;
    if (c >= C) return;
    float u[16];
    float mx = -1e30f;
#pragma unroll
    for (int p = 0; p < 16; ++p) if (p < P) { u[p] = br[c * P + p] * 2.0f; mx = fmaxf(mx, u[p]); }
    float se = 0.f;
#pragma unroll
    for (int p = 0; p < 16; ++p) if (p < P) se += expf(u[p] - mx);
    float lse = mx + logf(se);
    float mx2 = -1e30f;
#pragma unroll
    for (int p = 0; p < 16; ++p) if (p < P) { u[p] = (u[p] - lse) / t; mx2 = fmaxf(mx2, u[p]); }
    float se2 = 0.f;
#pragma unroll
    for (int p = 0; p < 16; ++p) if (p < P) { u[p] = expf(u[p] - mx2); se2 += u[p]; }
#pragma unroll
    for (int p = 0; p < 16; ++p) if (p < P) D[off + c * P + p] = u[p] / se2;
}

// h1[a,b,i] = relu( sum_f f[a,b,f]*fw1[a,f,i] + fb1[a,i] ); f stored (h,w,c),
// fw1 indexed (c,h,w)
__global__ __launch_bounds__(128) void fc1_k(const float* __restrict__ f,
                                             const float* __restrict__ w1,
                                             const float* __restrict__ b1,
                                             float* __restrict__ h1)
{
    const int a = blockIdx.x >> 4;
    const int b = blockIdx.x & 15;
    const int i = threadIdx.x;
    const float* fv = f + ((size_t)a * 16 + b) * 1568;
    const float* wv = w1 + (size_t)a * 1568 * 128 + i;
    float acc = b1[a * 128 + i];
    for (int hw = 0; hw < 49; ++hw)
        for (int c = 0; c < 32; ++c)
            acc = fmaf(fv[hw * 32 + c], wv[(size_t)(c * 49 + hw) * 128], acc);
    h1[((size_t)a * 16 + b) * 128 + i] = fmaxf(acc, 0.f);
}

__global__ __launch_bounds__(128) void fc23_k(const float* __restrict__ h1,
                                              const float* __restrict__ w2,
                                              const float* __restrict__ b2,
                                              const float* __restrict__ w3,
                                              const float* __restrict__ b3,
                                              float* __restrict__ out)
{
    __shared__ float sh1[16][128];
    __shared__ float sh2[16][128];
    const int a = blockIdx.x;
    const int i = threadIdx.x;
    for (int b = 0; b < 16; ++b) sh1[b][i] = h1[((size_t)a * 16 + b) * 128 + i];
    __syncthreads();
    float acc[16];
#pragma unroll
    for (int b = 0; b < 16; ++b) acc[b] = b2[a * 128 + i];
    for (int ff = 0; ff < 128; ++ff) {
        float wv = w2[((size_t)a * 128 + ff) * 128 + i];
#pragma unroll
        for (int b = 0; b < 16; ++b) acc[b] = fmaf(sh1[b][ff], wv, acc[b]);
    }
    for (int b = 0; b < 16; ++b) sh2[b][i] = fmaxf(acc[b], 0.f);
    __syncthreads();
    if (i < 16) {
        float o = b3[a];
        for (int ff = 0; ff < 128; ++ff) o = fmaf(sh2[i][ff], w3[a * 128 + ff], o);
        out[i * 40 + a] = o;
    }
}

extern "C" void kernel_launch(void* const* d_in, const int* in_sizes, int n_in,
                              void* d_out, int out_size, void* d_ws, size_t ws_size,
                              hipStream_t stream)
{
    (void)in_sizes; (void)n_in;

    const float* x   = (const float*)d_in[0];
    const float* w10 = (const float*)d_in[1];
    const float* wa[4] = {(const float*)d_in[3],  (const float*)d_in[7],
                          (const float*)d_in[11], (const float*)d_in[15]};
    const float* wb[4] = {(const float*)d_in[5],  (const float*)d_in[9],
                          (const float*)d_in[13], (const float*)d_in[17]};
    const float* br[4] = {(const float*)d_in[19], (const float*)d_in[20],
                          (const float*)d_in[21], (const float*)d_in[22]};
    const float* fw1 = (const float*)d_in[23];
    const float* fb1 = (const float*)d_in[24];
    const float* fw2 = (const float*)d_in[25];
    const float* fb2 = (const float*)d_in[26];
    const float* fw3 = (const float*)d_in[27];
    const float* fb3 = (const float*)d_in[28];
    float* out = (float*)d_out;

    const int Pl[4]  = {2, 4, 8, 16};
    const int CBs[4] = {64, 64, 64, 32};

    // ---- workspace arenas (f32 units); total 60,264,704 f32 = 241.06 MB ----
    const size_t NEED = 60264704ull * 4ull;
    if (ws_size < NEED) {
        hipMemsetAsync(d_out, 0, (size_t)out_size * sizeof(float), stream);
        return;
    }
    float* ws = (float*)d_ws;
    size_t o = 0;
    __bf16* WT1H = (__bf16*)(ws + o); o += 7168;   // 14336 bf16
    __bf16* WT1L = (__bf16*)(ws + o); o += 7168;
    __bf16 *WTAH[4], *WTAL[4], *WTBH[4], *WTBL[4];
    for (int L = 0; L < 4; ++L) {                  // P*72*512 bf16 each
        WTAH[L] = (__bf16*)(ws + o); o += (size_t)Pl[L] * 18432;
        WTAL[L] = (__bf16*)(ws + o); o += (size_t)Pl[L] * 18432;
        WTBH[L] = (__bf16*)(ws + o); o += (size_t)Pl[L] * 18432;
        WTBL[L] = (__bf16*)(ws + o); o += (size_t)Pl[L] * 18432;
    }
    float*  D     = ws + o; o += 1024;
    float2* STATS = (float2*)(ws + o); o += 4352;
    float2* STATS_C1 = STATS;
    float2* STATS_A  = STATS + 64;
    float2* STATS_B  = STATS + 1088;
    float*  H1 = ws + o; o += 81920;
    float*  A6 = ws + o; o += 524288;      // small conv partials
    float*  A5 = ws + o; o += 7872512;     // pooled raw / conv1 partials
    float*  A4 = ws + o; o += 16000000;    // raw conv outputs (fp32 NHWC)
    float*  A3 = ws + o; o += 16777216;    // split bufs (hi/lo bf16) / xc
    float*  A2 = ws + o; o += 16777216;    // Y / XB chain

    float2* PART   = (float2*)A6;
    float2* PARTC1 = (float2*)A5;
    __bf16* xcH = (__bf16*)A3;
    __bf16* xcL = (__bf16*)(A3 + 2097152);
    __bf16* A2H = (__bf16*)A2;             // hi at A2[0:], lo after
    __bf16* A2L = (__bf16*)(A2 + 8388608);
    __bf16* A3H = (__bf16*)A3;
    __bf16* A3L = (__bf16*)(A3 + 8388608);

    // ---- weights + mix coefficients + conv1 input prep ----
    prep_x<<<4096, 256, 0, stream>>>(x, xcH, xcL);
    wtrans1<<<56, 256, 0, stream>>>(w10, WT1H, WT1L);
    for (int L = 0; L < 4; ++L) {
        int tA = Pl[L] * 72 * 512;
        wtrans3<<<DIVUP(tA, 256), 256, 0, stream>>>(wa[L], WTAH[L], WTAL[L], Pl[L], 64);
        wtrans3<<<DIVUP(tA, 256), 256, 0, stream>>>(wb[L], WTBH[L], WTBL[L], Pl[L], CBs[L]);
    }
    dcalc<<<4, 64, 0, stream>>>(br[0], br[1], br[2], br[3], d_in[29], D);

    // ---- conv1: xc -> pooled raw A4 [16,125,125,64] + stats ----
    conv_mfma<1, 1><<<dim3(7813, 1, 1), 256, 0, stream>>>(
        xcH, xcL, 0, WT1H, WT1L, A4, 0, PARTC1,
        256, 256, 250, 250, 64, 1000000, 7, 125, 125, 125, 125);
    bn_finalize<<<64, 256, 0, stream>>>(PARTC1, 7813, 1.0 / 1000000.0, STATS_C1);
    // Y = bn_split(A4) -> A2 padded [16][127][127][64]
    bn_split<<<DIVUP(16 * 127 * 127 * 16, 256), 256, 0, stream>>>(
        A4, STATS_C1, A2H, A2L, 125, 125, 16 * 127 * 127 * 16);

    // ---- layer 0 (per parent; Y shared) ----
    for (int p = 0; p < 2; ++p) {
        conv_mfma<0, 0><<<dim3(1954, 1, 1), 256, 0, stream>>>(
            A2H, A2L, 0, WTAH[0] + (size_t)p * 36864, WTAL[0] + (size_t)p * 36864,
            A4, 0, PART, 127, 127, 125, 125, 64, 250000, 18, 0, 0, 1, 1);
        bn_finalize<<<64, 256, 0, stream>>>(PART, 1954, 1.0 / 250000.0, STATS_A);
        bn_split<<<DIVUP(16 * 127 * 127 * 16, 256), 256, 0, stream>>>(
            A4, STATS_A, A3H, A3L, 125, 125, 16 * 127 * 127 * 16);
        conv_mfma<1, 0><<<dim3(1985, 1, 1), 256, 0, stream>>>(
            A3H, A3L, 0, WTBH[0] + (size_t)p * 36864, WTBL[0] + (size_t)p * 36864,
            A5 + (size_t)p * 3936256, 0, PART,
            127, 127, 125, 125, 64, 254016, 18, 62, 62, 63, 63);
        bn_finalize<<<64, 256, 0, stream>>>(PART, 1985, 1.0 / 250000.0, STATS_B + p * 64);
    }
    mix_split<<<DIVUP(4 * 16 * 64 * 64 * 16, 256), 256, 0, stream>>>(
        A5, STATS_B, D + 0, A2H, A2L, 62, 62, 2, 3936256, 4 * 16 * 64 * 64 * 16);

    // ---- layer 1 (z=4) ----
    conv_mfma<0, 0><<<dim3(481, 1, 4), 256, 0, stream>>>(
        A2H, A2L, 4194304, WTAH[1], WTAL[1], A4, 3936256, PART,
        64, 64, 62, 62, 64, 61504, 18, 0, 0, 1, 1);
    bn_finalize<<<256, 256, 0, stream>>>(PART, 481, 1.0 / 61504.0, STATS_A);
    bn_split<<<DIVUP(64 * 64 * 64 * 16, 256), 256, 0, stream>>>(
        A4, STATS_A, A3H, A3L, 62, 62, 64 * 64 * 64 * 16);
    conv_mfma<1, 0><<<dim3(481, 1, 4), 256, 0, stream>>>(
        A3H, A3L, 4194304, WTBH[1], WTBL[1], A5, 984064, PART,
        64, 64, 62, 62, 64, 61504, 18, 31, 31, 31, 31);
    bn_finalize<<<256, 256, 0, stream>>>(PART, 481, 1.0 / 61504.0, STATS_B);
    mix_split<<<DIVUP(8 * 16 * 33 * 33 * 16, 256), 256, 0, stream>>>(
        A5, STATS_B, D + 8, A2H, A2L, 31, 31, 4, 984064, 8 * 16 * 33 * 33 * 16);

    // ---- layer 2 (z=8) ----
    conv_mfma<0, 0><<<dim3(121, 1, 8), 256, 0, stream>>>(
        A2H, A2L, 1115136, WTAH[2], WTAL[2], A4, 984064, PART,
        33, 33, 31, 31, 64, 15376, 18, 0, 0, 1, 1);
    bn_finalize<<<512, 256, 0, stream>>>(PART, 121, 1.0 / 15376.0, STATS_A);
    bn_split<<<DIVUP(128 * 33 * 33 * 16, 256), 256, 0, stream>>>(
        A4, STATS_A, A3H, A3L, 31, 31, 128 * 33 * 33 * 16);
    conv_mfma<1, 0><<<dim3(128, 1, 8), 256, 0, stream>>>(
        A3H, A3L, 1115136, WTBH[2], WTBL[2], A5, 230400, PART,
        33, 33, 31, 31, 64, 16384, 18, 15, 15, 16, 16);
    bn_finalize<<<512, 256, 0, stream>>>(PART, 128, 1.0 / 15376.0, STATS_B);
    mix_split<<<DIVUP(16 * 16 * 17 * 17 * 16, 256), 256, 0, stream>>>(
        A5, STATS_B, D + 40, A2H, A2L, 15, 15, 8, 230400, 16 * 16 * 17 * 17 * 16);

    // ---- layer 3 (z=16) ----
    conv_mfma<0, 0><<<dim3(29, 1, 16), 256, 0, stream>>>(
        A2H, A2L, 295936, WTAH[3], WTAL[3], A4, 230400, PART,
        17, 17, 15, 15, 64, 3600, 18, 0, 0, 1, 1);
    bn_finalize<<<1024, 256, 0, stream>>>(PART, 29, 1.0 / 3600.0, STATS_A);
    bn_split<<<DIVUP(256 * 17 * 17 * 16, 256), 256, 0, stream>>>(
        A4, STATS_A, A3H, A3L, 15, 15, 256 * 17 * 17 * 16);
    conv_mfma<1, 0><<<dim3(32, 1, 16), 256, 0, stream>>>(
        A3H, A3L, 295936, WTBH[3], WTBL[3], A5, 25088, PART,
        17, 17, 15, 15, 32, 4096, 18, 7, 7, 8, 8);
    bn_finalize<<<1024, 256, 0, stream>>>(PART, 32, 1.0 / 3600.0, STATS_B);
    mix_last<<<DIVUP(40 * 16 * 49 * 32, 256), 256, 0, stream>>>(
        A5, STATS_B, D + 168, A2, 40 * 16 * 49 * 32);

    // ---- FC heads ----
    fc1_k<<<640, 128, 0, stream>>>(A2, fw1, fb1, H1);
    fc23_k<<<40, 128, 0, stream>>>(H1, fw2, fb2, fw3, fb3, out);
}

// Round 13
// 1012.187 us; speedup vs baseline: 1.3191x; 1.1463x over previous
//
#include <hip/hip_runtime.h>
#include <math.h>

#define DIVUP(a,b) (((a)+(b)-1)/(b))

typedef _Float16 f16x8 __attribute__((ext_vector_type(8)));
typedef _Float16 f16x4 __attribute__((ext_vector_type(4)));
typedef float    f32x4 __attribute__((ext_vector_type(4)));

// ---------------------------------------------------------------------------
// Implicit-GEMM conv, NHWC, fp16 2-MFMA scheme: A = aH + aL (fp16 hi/lo,
// ~22 mantissa bits), W = single fp16 (2^-11 weight rounding);
// acc += aH*b + aL*b. 16 MFMA / wave / K-step. BM=128, BN=64, BK=32.
// A:   direct global->VGPR in frag layout, double-buffered in named reg sets,
//      UNCONDITIONAL loads (invalid rows clamp to base 0; masked at stats
//      emit + C-write guards).
// B:   staged to LDS [64][40], double-buffered, ONE barrier per K-step.
// XCD-aware bijective block swizzle (m204). POOL=1: quad-M + fused maxpool.
// Emits per-block per-channel (sum,sumsq) partials.
// ---------------------------------------------------------------------------
template<int POOL, int C1>
__global__ __launch_bounds__(256, 4) void conv_mfma(
    const _Float16* __restrict__ inH, const _Float16* __restrict__ inL, long inZstride,
    const _Float16* __restrict__ wt,
    float* __restrict__ out, long outZstride, float2* __restrict__ part,
    int HinP, int WinP, int Hout, int Wout, int Cout, int M, int niter,
    int H2, int W2, int H2c, int W2c)
{
    __shared__ __align__(16) char smem[10240];   // B dbuf: 2 x 5120
    __shared__ __align__(16) float2 red[64 * 17];

    // ---- bijective XCD swizzle (m204) ----
    int bx;
    {
        int n = gridDim.x, orig = blockIdx.x;
        int q = n >> 3, r = n & 7;
        int xcd = orig & 7, idx = orig >> 3;
        bx = (xcd < r ? xcd * (q + 1) : r * (q + 1) + (xcd - r) * q) + idx;
    }

    const int tid  = threadIdx.x;
    const int wv   = tid >> 6;
    const int ln15 = tid & 15;
    const int lhi  = (tid >> 4) & 3;
    const int sn   = tid & 63;        // B stage: n row this thread stages
    const int skb  = tid >> 6;        // B stage: kb slot
    const int sdst = sn * 40 + skb * 8;

    const _Float16* ipH = inH + (size_t)blockIdx.z * inZstride;
    const _Float16* ipL = inL + (size_t)blockIdx.z * inZstride;

    auto pixbase = [&](int mA) -> int {
        int nb, h, w; bool valid;
        if (POOL) {
            int r = mA & 3, quad = mA >> 2;
            int cpi = H2c * W2c;
            nb = quad / cpi;
            int rem = quad - nb * cpi;
            int h2 = rem / W2c, w2 = rem - h2 * W2c;
            h = h2 * 2 + (r >> 1); w = w2 * 2 + (r & 1);
            valid = (mA < M) && (h < Hout) && (w < Wout);
        } else {
            int HW = Hout * Wout;
            valid = mA < M;
            int mm = valid ? mA : 0;
            nb = mm / HW;
            int rem = mm - nb * HW;
            h = rem / Wout; w = rem - h * Wout;
        }
        if (!valid) { nb = 0; h = 0; w = 0; }
        if (C1) return ((nb * 256 + h) * 256 + w) * 4;
        return ((nb * HinP + h) * WinP + w) * 64;
    };
    auto rowvalid = [&](int mA) -> bool {
        if (POOL) {
            int r = mA & 3, quad = mA >> 2;
            int cpi = H2c * W2c;
            int nb = quad / cpi;
            int rem = quad - nb * cpi;
            int h2 = rem / W2c, w2 = rem - h2 * W2c;
            int h = h2 * 2 + (r >> 1), w = w2 * 2 + (r & 1);
            return (mA < M) && (h < Hout) && (w < Wout);
        }
        return mA < M;
    };

    int abase[2];
#pragma unroll
    for (int q = 0; q < 2; ++q)
        abase[q] = pixbase(bx * 128 + wv * 32 + q * 16 + ln15);

    unsigned vmask = 0;
#pragma unroll
    for (int q = 0; q < 2; ++q)
#pragma unroll
        for (int r = 0; r < 4; ++r)
            vmask |= (unsigned)rowvalid(bx * 128 + wv * 32 + q * 16 + lhi * 4 + r)
                     << (q * 4 + r);

    const _Float16* wp = wt + (size_t)blockIdx.z * niter * 2048;

    auto loadA = [&](int it, f16x8 (&aH)[2], f16x8 (&aL)[2]) {
        int off;
        if (C1) off = it * 1024 + lhi * 8;
        else { int tap = it >> 1; int kh = tap / 3, kw = tap - 3 * kh;
               off = (kh * WinP + kw) * 64 + (it & 1) * 32 + lhi * 8; }
#pragma unroll
        for (int q = 0; q < 2; ++q) {
            aH[q] = *(const f16x8*)(ipH + abase[q] + off);
            aL[q] = *(const f16x8*)(ipL + abase[q] + off);
        }
    };

    f32x4 acc[2][4] = {};
    f16x8 a0H[2], a0L[2], a1H[2], a1L[2];
    f16x8 sb;

    // ---- prologue: buf0 <- B(0); a0 <- A(0); a1 <- A(1); sb <- B(1) ----
    {
        f16x8 h = *(const f16x8*)(wp + (size_t)(skb * 64 + sn) * 8);
        *(f16x8*)((_Float16*)smem + sdst) = h;
        loadA(0, a0H, a0L);
        if (niter > 1) {
            loadA(1, a1H, a1L);
            sb = *(const f16x8*)(wp + (size_t)((4 + skb) * 64 + sn) * 8);
        }
        __syncthreads();
    }

#define REGION(IT, CUR, AH, AL)                                                   \
    {                                                                             \
        const int itc = (IT);                                                     \
        if (itc + 1 < niter)                                                      \
            *(f16x8*)((_Float16*)(smem + ((CUR) ^ 1) * 5120) + sdst) = sb;        \
        const _Float16* rb = (const _Float16*)(smem + (CUR) * 5120);              \
        f16x8 bf[4];                                                              \
        _Pragma("unroll")                                                         \
        for (int t = 0; t < 4; ++t)                                               \
            bf[t] = *(const f16x8*)(rb + (t * 16 + ln15) * 40 + lhi * 8);         \
        if (itc + 2 < niter)                                                      \
            sb = *(const f16x8*)(wp +                                             \
                     (size_t)(((itc + 2) * 4 + skb) * 64 + sn) * 8);              \
        _Pragma("unroll")                                                         \
        for (int t = 0; t < 4; ++t)                                               \
            _Pragma("unroll")                                                     \
            for (int q = 0; q < 2; ++q)                                           \
                acc[q][t] = __builtin_amdgcn_mfma_f32_16x16x32_f16(AH[q], bf[t], acc[q][t], 0, 0, 0); \
        _Pragma("unroll")                                                         \
        for (int t = 0; t < 4; ++t)                                               \
            _Pragma("unroll")                                                     \
            for (int q = 0; q < 2; ++q)                                           \
                acc[q][t] = __builtin_amdgcn_mfma_f32_16x16x32_f16(AL[q], bf[t], acc[q][t], 0, 0, 0); \
        if (itc + 2 < niter) loadA(itc + 2, AH, AL);                              \
        __syncthreads();                                                          \
    }

    for (int it = 0; it < niter; it += 2) {
        REGION(it, 0, a0H, a0L);
        if (it + 1 < niter) REGION(it + 1, 1, a1H, a1L);
    }
#undef REGION

    // ---- per-block per-channel (sum,sumsq) partials (masked rows) ----
#pragma unroll
    for (int t = 0; t < 4; ++t) {
        float s = 0.f, s2 = 0.f;
#pragma unroll
        for (int q = 0; q < 2; ++q)
#pragma unroll
            for (int r = 0; r < 4; ++r) {
                float v = ((vmask >> (q * 4 + r)) & 1u) ? acc[q][t][r] : 0.f;
                s += v; s2 += v * v;
            }
        red[(ln15 + 16 * t) * 17 + (wv * 4 + lhi)] = make_float2(s, s2);
    }
    __syncthreads();
    if (tid < 64) {
        float s = 0.f, s2 = 0.f;
#pragma unroll
        for (int q = 0; q < 16; ++q) { float2 v = red[tid * 17 + q]; s += v.x; s2 += v.y; }
        part[((size_t)blockIdx.z * 64 + tid) * gridDim.x + bx] = make_float2(s, s2);
    }

    // ---- NHWC output ----
    float* zout = out + (size_t)blockIdx.z * outZstride;
#pragma unroll
    for (int q = 0; q < 2; ++q) {
        const int mbase = bx * 128 + wv * 32 + q * 16 + lhi * 4;
        if (POOL) {
            if (mbase < M) {
                int quad = mbase >> 2;
                int cpi  = H2c * W2c;
                int nb2  = quad / cpi;
                int rem  = quad - nb2 * cpi;
                int h2 = rem / W2c, w2 = rem - h2 * W2c;
                if (h2 < H2 && w2 < W2) {
                    float* op = zout + ((size_t)(nb2 * H2 + h2) * W2 + w2) * Cout;
#pragma unroll
                    for (int t = 0; t < 4; ++t) {
                        int n = ln15 + 16 * t;
                        if (n < Cout) {
                            float mx = fmaxf(fmaxf(acc[q][t][0], acc[q][t][1]),
                                             fmaxf(acc[q][t][2], acc[q][t][3]));
                            op[n] = mx;
                        }
                    }
                }
            }
        } else {
#pragma unroll
            for (int r = 0; r < 4; ++r) {
                int m = mbase + r;
                if (m < M) {
                    float* op = zout + (size_t)m * Cout;
#pragma unroll
                    for (int t = 0; t < 4; ++t) {
                        int n = ln15 + 16 * t;
                        if (n < Cout) op[n] = acc[q][t][r];
                    }
                }
            }
        }
    }
}

// partials -> (mean, rsqrt(var+eps)) per (z,channel)
__global__ __launch_bounds__(256) void bn_finalize(const float2* __restrict__ part,
                                                   int nblkx, double Ninv,
                                                   float2* __restrict__ stats)
{
    __shared__ double sh[512];
    const int zc = blockIdx.x, tid = threadIdx.x;
    const float2* p = part + (size_t)zc * nblkx;
    double s = 0, s2 = 0;
    for (int i = tid; i < nblkx; i += 256) { s += p[i].x; s2 += p[i].y; }
    sh[tid] = s; sh[256 + tid] = s2;
    __syncthreads();
    for (int st = 128; st > 0; st >>= 1) {
        if (tid < st) { sh[tid] += sh[tid + st]; sh[256 + tid] += sh[256 + tid + st]; }
        __syncthreads();
    }
    if (tid == 0) {
        float mean = (float)(sh[0] * Ninv);
        float var  = (float)(sh[256] * Ninv - (double)mean * (double)mean);
        if (var < 0.f) var = 0.f;
        stats[zc] = make_float2(mean, rsqrtf(var + 1e-5f));
    }
}

// raw NHWC fp32 + stats -> padded NHWC fp16 hi/lo with zero border.
__global__ void bn_split(const float* __restrict__ raw, const float2* __restrict__ stats,
                         _Float16* __restrict__ outH, _Float16* __restrict__ outL,
                         int H, int W, int total)
{
    int idx = blockIdx.x * 256 + threadIdx.x;
    if (idx >= total) return;
    const int Hp = H + 2, Wp = W + 2;
    int c4 = idx & 15;
    int t  = idx >> 4;
    int wp = t % Wp; t /= Wp;
    int hp = t % Hp; int img = t / Hp;
    size_t o = (((size_t)img * Hp + hp) * Wp + wp) * 64 + c4 * 4;
    f16x4 hi, lo;
    if (hp == 0 || hp == Hp - 1 || wp == 0 || wp == Wp - 1) {
#pragma unroll
        for (int j = 0; j < 4; ++j) { hi[j] = (_Float16)0.f; lo[j] = (_Float16)0.f; }
    } else {
        float4 v = *(const float4*)(raw + (((size_t)img * H + (hp - 1)) * W + (wp - 1)) * 64 + c4 * 4);
        const float2* st = stats + (img >> 4) * 64 + c4 * 4;
        float vv[4] = {v.x, v.y, v.z, v.w};
#pragma unroll
        for (int j = 0; j < 4; ++j) {
            float2 s = st[j];
            float r = fmaxf((vv[j] - s.x) * s.y, 0.f);
            _Float16 hh = (_Float16)r;
            hi[j] = hh; lo[j] = (_Float16)(r - (float)hh);
        }
    }
    *(f16x4*)(outH + o) = hi;
    *(f16x4*)(outL + o) = lo;
}

// pooled NHWC [P][16][H][W][64] + stats + d -> XB padded fp16 hi/lo
__global__ void mix_split(const float* __restrict__ pooled, const float2* __restrict__ stats,
                          const float* __restrict__ d,
                          _Float16* __restrict__ outH, _Float16* __restrict__ outL,
                          int H, int W, int P, long strideP, int total)
{
    int idx = blockIdx.x * 256 + threadIdx.x;
    if (idx >= total) return;
    const int Hp = H + 2, Wp = W + 2;
    int c4 = idx & 15;
    int t  = idx >> 4;
    int wp = t % Wp; t /= Wp;
    int hp = t % Hp; t /= Hp;
    int n  = t & 15;
    int cc = t >> 4;
    size_t o = (((size_t)(cc * 16 + n) * Hp + hp) * Wp + wp) * 64 + c4 * 4;
    f16x4 hi, lo;
    if (hp == 0 || hp == Hp - 1 || wp == 0 || wp == Wp - 1) {
#pragma unroll
        for (int j = 0; j < 4; ++j) { hi[j] = (_Float16)0.f; lo[j] = (_Float16)0.f; }
    } else {
        float a[4] = {0.f, 0.f, 0.f, 0.f};
        const float* pb = pooled + (((size_t)n * H + (hp - 1)) * W + (wp - 1)) * 64 + c4 * 4;
        for (int p = 0; p < P; ++p) {
            float4 v = *(const float4*)(pb + (size_t)p * strideP);
            const float2* st = stats + p * 64 + c4 * 4;
            float dc = d[cc * P + p];
            float vv[4] = {v.x, v.y, v.z, v.w};
#pragma unroll
            for (int j = 0; j < 4; ++j) {
                float2 s = st[j];
                a[j] = fmaf(dc, fmaxf((vv[j] - s.x) * s.y, 0.f), a[j]);
            }
        }
#pragma unroll
        for (int j = 0; j < 4; ++j) {
            _Float16 hh = (_Float16)a[j];
            hi[j] = hh; lo[j] = (_Float16)(a[j] - (float)hh);
        }
    }
    *(f16x4*)(outH + o) = hi;
    *(f16x4*)(outL + o) = lo;
}

// L3 mix: pooled [16][16][7][7][32] -> XB3 fp32 [40][16][7][7][32]
__global__ void mix_last(const float* __restrict__ pooled, const float2* __restrict__ stats,
                         const float* __restrict__ d, float* __restrict__ out, int total)
{
    int idx = blockIdx.x * 256 + threadIdx.x;
    if (idx >= total) return;
    int c  = idx & 31;
    int t  = idx >> 5;
    int hw = t % 49; t /= 49;
    int n  = t & 15;
    int a  = t >> 4;
    float acc = 0.f;
    const float* pb = pooled + ((size_t)n * 49 + hw) * 32 + c;
    for (int p = 0; p < 16; ++p) {
        float2 s = stats[p * 64 + c];
        acc = fmaf(d[a * 16 + p], fmaxf((pb[(size_t)p * 25088] - s.x) * s.y, 0.f), acc);
    }
    out[idx] = acc;
}

// x NCHW [16][3][256][256] -> packed NHWC4 fp16 hi/lo [16][256][256][4]
__global__ void prep_x(const float* __restrict__ x, _Float16* __restrict__ xH,
                       _Float16* __restrict__ xL)
{
    int idx = blockIdx.x * 256 + threadIdx.x;   // 16*65536
    if (idx >= 16 * 65536) return;
    int n = idx >> 16, hw = idx & 65535;
    f16x4 hi, lo;
#pragma unroll
    for (int ci = 0; ci < 3; ++ci) {
        float v = x[((size_t)n * 3 + ci) * 65536 + hw];
        _Float16 hh = (_Float16)v;
        hi[ci] = hh; lo[ci] = (_Float16)(v - (float)hh);
    }
    hi[3] = (_Float16)0.f; lo[3] = (_Float16)0.f;
    *(f16x4*)(xH + (size_t)idx * 4) = hi;
    *(f16x4*)(xL + (size_t)idx * 4) = lo;
}

// conv1 weights [64][3][7][7] -> fp16 panel [28 kblk][64][8], k=kh*32+kw*4+ci
__global__ void wtrans1(const float* __restrict__ w, _Float16* __restrict__ wt)
{
    int i = blockIdx.x * 256 + threadIdx.x;
    if (i >= 28 * 512) return;
    int j = i & 7, n = (i >> 3) & 63, kb = i >> 9;
    int k = kb * 8 + j;
    int kh = k >> 5, r = k & 31, kw = r >> 2, ci = r & 3;
    float v = (kw < 7 && ci < 3) ? w[((n * 3 + ci) * 7 + kh) * 7 + kw] : 0.f;
    wt[i] = (_Float16)v;
}

// 3x3 weights [P][Cout][64][3][3] -> fp16 panels [p][72 kblk][64][8],
// k = (kh*3+kw)*64 + ci
__global__ void wtrans3(const float* __restrict__ w, _Float16* __restrict__ wt,
                        int P, int Cout)
{
    int total = P * 72 * 512;
    for (int i = blockIdx.x * 256 + threadIdx.x; i < total; i += gridDim.x * 256) {
        int j = i & 7, n = (i >> 3) & 63, kb = (i >> 9) % 72, p = (i >> 9) / 72;
        int k = kb * 8 + j;
        int ci = k & 63, tap = k >> 6, kh = tap / 3, kw = tap - 3 * kh;
        float v = (n < Cout) ? w[(((size_t)(p * Cout + n)) * 64 + ci) * 9 + kh * 3 + kw] : 0.f;
        wt[i] = (_Float16)v;
    }
}

// d = softmax_p( log(softmax_p(br*2)) / t ) for all 4 layers
__global__ void dcalc(const float* __restrict__ br0, const float* __restrict__ br1,
                      const float* __restrict__ br2, const float* __restrict__ br3,
                      const void* __restrict__ tptr, float* __restrict__ D)
{
    const int L = blockIdx.x;
    const float* br; int C, P, off;
    if      (L == 0) { br = br0; C = 4;  P = 2;  off = 0;   }
    else if (L == 1) { br = br1; C = 8;  P = 4;  off = 8;   }
    else if (L == 2) { br = br2; C = 16; P = 8;  off = 40;  }
    else             { br = br3; C = 40; P = 16; off = 168; }
    int ti = *(const int*)tptr;
    float t = (ti > 0 && ti < 1000000) ? (float)ti : *(const float*)tptr;
    const int c = threadIdx.x;
    if (c >= C) return;
    float u[16];
    float mx = -1e30f;
#pragma unroll
    for (int p = 0; p < 16; ++p) if (p < P) { u[p] = br[c * P + p] * 2.0f; mx = fmaxf(mx, u[p]); }
    float se = 0.f;
#pragma unroll
    for (int p = 0; p < 16; ++p) if (p < P) se += expf(u[p] - mx);
    float lse = mx + logf(se);
    float mx2 = -1e30f;
#pragma unroll
    for (int p = 0; p < 16; ++p) if (p < P) { u[p] = (u[p] - lse) / t; mx2 = fmaxf(mx2, u[p]); }
    float se2 = 0.f;
#pragma unroll
    for (int p = 0; p < 16; ++p) if (p < P) { u[p] = expf(u[p] - mx2); se2 += u[p]; }
#pragma unroll
    for (int p = 0; p < 16; ++p) if (p < P) D[off + c * P + p] = u[p] / se2;
}

// h1[a,b,i] = relu( sum_f f[a,b,f]*fw1[a,f,i] + fb1[a,i] ); f stored (h,w,c),
// fw1 indexed (c,h,w)
__global__ __launch_bounds__(128) void fc1_k(const float* __restrict__ f,
                                             const float* __restrict__ w1,
                                             const float* __restrict__ b1,
                                             float* __restrict__ h1)
{
    const int a = blockIdx.x >> 4;
    const int b = blockIdx.x & 15;
    const int i = threadIdx.x;
    const float* fv = f + ((size_t)a * 16 + b) * 1568;
    const float* wv = w1 + (size_t)a * 1568 * 128 + i;
    float acc = b1[a * 128 + i];
    for (int hw = 0; hw < 49; ++hw)
        for (int c = 0; c < 32; ++c)
            acc = fmaf(fv[hw * 32 + c], wv[(size_t)(c * 49 + hw) * 128], acc);
    h1[((size_t)a * 16 + b) * 128 + i] = fmaxf(acc, 0.f);
}

__global__ __launch_bounds__(128) void fc23_k(const float* __restrict__ h1,
                                              const float* __restrict__ w2,
                                              const float* __restrict__ b2,
                                              const float* __restrict__ w3,
                                              const float* __restrict__ b3,
                                              float* __restrict__ out)
{
    __shared__ float sh1[16][128];
    __shared__ float sh2[16][128];
    const int a = blockIdx.x;
    const int i = threadIdx.x;
    for (int b = 0; b < 16; ++b) sh1[b][i] = h1[((size_t)a * 16 + b) * 128 + i];
    __syncthreads();
    float acc[16];
#pragma unroll
    for (int b = 0; b < 16; ++b) acc[b] = b2[a * 128 + i];
    for (int ff = 0; ff < 128; ++ff) {
        float wv = w2[((size_t)a * 128 + ff) * 128 + i];
#pragma unroll
        for (int b = 0; b < 16; ++b) acc[b] = fmaf(sh1[b][ff], wv, acc[b]);
    }
    for (int b = 0; b < 16; ++b) sh2[b][i] = fmaxf(acc[b], 0.f);
    __syncthreads();
    if (i < 16) {
        float o = b3[a];
        for (int ff = 0; ff < 128; ++ff) o = fmaf(sh2[i][ff], w3[a * 128 + ff], o);
        out[i * 40 + a] = o;
    }
}

extern "C" void kernel_launch(void* const* d_in, const int* in_sizes, int n_in,
                              void* d_out, int out_size, void* d_ws, size_t ws_size,
                              hipStream_t stream)
{
    (void)in_sizes; (void)n_in;

    const float* x   = (const float*)d_in[0];
    const float* w10 = (const float*)d_in[1];
    const float* wa[4] = {(const float*)d_in[3],  (const float*)d_in[7],
                          (const float*)d_in[11], (const float*)d_in[15]};
    const float* wb[4] = {(const float*)d_in[5],  (const float*)d_in[9],
                          (const float*)d_in[13], (const float*)d_in[17]};
    const float* br[4] = {(const float*)d_in[19], (const float*)d_in[20],
                          (const float*)d_in[21], (const float*)d_in[22]};
    const float* fw1 = (const float*)d_in[23];
    const float* fb1 = (const float*)d_in[24];
    const float* fw2 = (const float*)d_in[25];
    const float* fb2 = (const float*)d_in[26];
    const float* fw3 = (const float*)d_in[27];
    const float* fb3 = (const float*)d_in[28];
    float* out = (float*)d_out;

    const int Pl[4]  = {2, 4, 8, 16};
    const int CBs[4] = {64, 64, 64, 32};

    // ---- workspace arenas (f32 units); total 59,151,616 f32 = 236.6 MB ----
    const size_t NEED = 59151616ull * 4ull;
    if (ws_size < NEED) {
        hipMemsetAsync(d_out, 0, (size_t)out_size * sizeof(float), stream);
        return;
    }
    float* ws = (float*)d_ws;
    size_t o = 0;
    _Float16* WT1 = (_Float16*)(ws + o); o += 7168;   // 14336 fp16
    _Float16 *WTA[4], *WTB[4];
    for (int L = 0; L < 4; ++L) {                     // P*72*512 fp16 each
        WTA[L] = (_Float16*)(ws + o); o += (size_t)Pl[L] * 18432;
        WTB[L] = (_Float16*)(ws + o); o += (size_t)Pl[L] * 18432;
    }
    float*  D     = ws + o; o += 1024;
    float2* STATS = (float2*)(ws + o); o += 4352;
    float2* STATS_C1 = STATS;
    float2* STATS_A  = STATS + 64;
    float2* STATS_B  = STATS + 1088;
    float*  H1 = ws + o; o += 81920;
    float*  A6 = ws + o; o += 524288;      // small conv partials
    float*  A5 = ws + o; o += 7872512;     // pooled raw / conv1 partials
    float*  A4 = ws + o; o += 16000000;    // raw conv outputs (fp32 NHWC)
    float*  A3 = ws + o; o += 16777216;    // split bufs (fp16 hi/lo) / xc
    float*  A2 = ws + o; o += 16777216;    // Y / XB chain

    float2* PART   = (float2*)A6;
    float2* PARTC1 = (float2*)A5;
    _Float16* xcH = (_Float16*)A3;
    _Float16* xcL = (_Float16*)(A3 + 2097152);
    _Float16* A2H = (_Float16*)A2;
    _Float16* A2L = (_Float16*)(A2 + 8388608);
    _Float16* A3H = (_Float16*)A3;
    _Float16* A3L = (_Float16*)(A3 + 8388608);

    // ---- weights + mix coefficients + conv1 input prep ----
    prep_x<<<4096, 256, 0, stream>>>(x, xcH, xcL);
    wtrans1<<<56, 256, 0, stream>>>(w10, WT1);
    for (int L = 0; L < 4; ++L) {
        int tA = Pl[L] * 72 * 512;
        wtrans3<<<DIVUP(tA, 256), 256, 0, stream>>>(wa[L], WTA[L], Pl[L], 64);
        wtrans3<<<DIVUP(tA, 256), 256, 0, stream>>>(wb[L], WTB[L], Pl[L], CBs[L]);
    }
    dcalc<<<4, 64, 0, stream>>>(br[0], br[1], br[2], br[3], d_in[29], D);

    // ---- conv1: xc -> pooled raw A4 [16,125,125,64] + stats ----
    conv_mfma<1, 1><<<dim3(7813, 1, 1), 256, 0, stream>>>(
        xcH, xcL, 0, WT1, A4, 0, PARTC1,
        256, 256, 250, 250, 64, 1000000, 7, 125, 125, 125, 125);
    bn_finalize<<<64, 256, 0, stream>>>(PARTC1, 7813, 1.0 / 1000000.0, STATS_C1);
    bn_split<<<DIVUP(16 * 127 * 127 * 16, 256), 256, 0, stream>>>(
        A4, STATS_C1, A2H, A2L, 125, 125, 16 * 127 * 127 * 16);

    // ---- layer 0 (per parent; Y shared) ----
    for (int p = 0; p < 2; ++p) {
        conv_mfma<0, 0><<<dim3(1954, 1, 1), 256, 0, stream>>>(
            A2H, A2L, 0, WTA[0] + (size_t)p * 36864, A4, 0, PART,
            127, 127, 125, 125, 64, 250000, 18, 0, 0, 1, 1);
        bn_finalize<<<64, 256, 0, stream>>>(PART, 1954, 1.0 / 250000.0, STATS_A);
        bn_split<<<DIVUP(16 * 127 * 127 * 16, 256), 256, 0, stream>>>(
            A4, STATS_A, A3H, A3L, 125, 125, 16 * 127 * 127 * 16);
        conv_mfma<1, 0><<<dim3(1985, 1, 1), 256, 0, stream>>>(
            A3H, A3L, 0, WTB[0] + (size_t)p * 36864, A5 + (size_t)p * 3936256, 0, PART,
            127, 127, 125, 125, 64, 254016, 18, 62, 62, 63, 63);
        bn_finalize<<<64, 256, 0, stream>>>(PART, 1985, 1.0 / 250000.0, STATS_B + p * 64);
    }
    mix_split<<<DIVUP(4 * 16 * 64 * 64 * 16, 256), 256, 0, stream>>>(
        A5, STATS_B, D + 0, A2H, A2L, 62, 62, 2, 3936256, 4 * 16 * 64 * 64 * 16);

    // ---- layer 1 (z=4) ----
    conv_mfma<0, 0><<<dim3(481, 1, 4), 256, 0, stream>>>(
        A2H, A2L, 4194304, WTA[1], A4, 3936256, PART,
        64, 64, 62, 62, 64, 61504, 18, 0, 0, 1, 1);
    bn_finalize<<<256, 256, 0, stream>>>(PART, 481, 1.0 / 61504.0, STATS_A);
    bn_split<<<DIVUP(64 * 64 * 64 * 16, 256), 256, 0, stream>>>(
        A4, STATS_A, A3H, A3L, 62, 62, 64 * 64 * 64 * 16);
    conv_mfma<1, 0><<<dim3(481, 1, 4), 256, 0, stream>>>(
        A3H, A3L, 4194304, WTB[1], A5, 984064, PART,
        64, 64, 62, 62, 64, 61504, 18, 31, 31, 31, 31);
    bn_finalize<<<256, 256, 0, stream>>>(PART, 481, 1.0 / 61504.0, STATS_B);
    mix_split<<<DIVUP(8 * 16 * 33 * 33 * 16, 256), 256, 0, stream>>>(
        A5, STATS_B, D + 8, A2H, A2L, 31, 31, 4, 984064, 8 * 16 * 33 * 33 * 16);

    // ---- layer 2 (z=8) ----
    conv_mfma<0, 0><<<dim3(121, 1, 8), 256, 0, stream>>>(
        A2H, A2L, 1115136, WTA[2], A4, 984064, PART,
        33, 33, 31, 31, 64, 15376, 18, 0, 0, 1, 1);
    bn_finalize<<<512, 256, 0, stream>>>(PART, 121, 1.0 / 15376.0, STATS_A);
    bn_split<<<DIVUP(128 * 33 * 33 * 16, 256), 256, 0, stream>>>(
        A4, STATS_A, A3H, A3L, 31, 31, 128 * 33 * 33 * 16);
    conv_mfma<1, 0><<<dim3(128, 1, 8), 256, 0, stream>>>(
        A3H, A3L, 1115136, WTB[2], A5, 230400, PART,
        33, 33, 31, 31, 64, 16384, 18, 15, 15, 16, 16);
    bn_finalize<<<512, 256, 0, stream>>>(PART, 128, 1.0 / 15376.0, STATS_B);
    mix_split<<<DIVUP(16 * 16 * 17 * 17 * 16, 256), 256, 0, stream>>>(
        A5, STATS_B, D + 40, A2H, A2L, 15, 15, 8, 230400, 16 * 16 * 17 * 17 * 16);

    // ---- layer 3 (z=16) ----
    conv_mfma<0, 0><<<dim3(29, 1, 16), 256, 0, stream>>>(
        A2H, A2L, 295936, WTA[3], A4, 230400, PART,
        17, 17, 15, 15, 64, 3600, 18, 0, 0, 1, 1);
    bn_finalize<<<1024, 256, 0, stream>>>(PART, 29, 1.0 / 3600.0, STATS_A);
    bn_split<<<DIVUP(256 * 17 * 17 * 16, 256), 256, 0, stream>>>(
        A4, STATS_A, A3H, A3L, 15, 15, 256 * 17 * 17 * 16);
    conv_mfma<1, 0><<<dim3(32, 1, 16), 256, 0, stream>>>(
        A3H, A3L, 295936, WTB[3], A5, 25088, PART,
        17, 17, 15, 15, 32, 4096, 18, 7, 7, 8, 8);
    bn_finalize<<<1024, 256, 0, stream>>>(PART, 32, 1.0 / 3600.0, STATS_B);
    mix_last<<<DIVUP(40 * 16 * 49 * 32, 256), 256, 0, stream>>>(
        A5, STATS_B, D + 168, A2, 40 * 16 * 49 * 32);

    // ---- FC heads ----
    fc1_k<<<640, 128, 0, stream>>>(A2, fw1, fb1, H1);
    fc23_k<<<40, 128, 0, stream>>>(H1, fw2, fb2, fw3, fb3, out);
}

// Round 14
// 1001.368 us; speedup vs baseline: 1.3333x; 1.0108x over previous
//
#include <hip/hip_runtime.h>
#include <math.h>

#define DIVUP(a,b) (((a)+(b)-1)/(b))

typedef _Float16 f16x8 __attribute__((ext_vector_type(8)));
typedef _Float16 f16x4 __attribute__((ext_vector_type(4)));
typedef float    f32x4 __attribute__((ext_vector_type(4)));

// ---------------------------------------------------------------------------
// Implicit-GEMM conv, NHWC, fp16 2-MFMA scheme: A = aH + aL (fp16 hi/lo,
// ~22 mantissa bits), W = single fp16; acc += aH*b + aL*b.
// 16 MFMA / wave / K-step. BM=128, BN=64, BK=32.
// ALL GEOMETRY IS COMPILE-TIME (template) -> div/mod become magic-muls.
// A: direct global->VGPR in frag layout, double-buffered named reg sets,
//    unconditional loads (invalid rows clamp to base 0; masked at stats
//    emit + C-write guards).
// B: staged to LDS [64][40], double-buffered, ONE barrier per K-step.
// Stats scratch overlays the B LDS after the K-loop (total LDS 10.2 KB).
// XCD-aware bijective block swizzle (m204). POOL=1: quad-M + fused maxpool.
// ---------------------------------------------------------------------------
template<int POOL, int C1, int HinP, int WinP, int Hout, int Wout, int Cout,
         int M, int NITER, int H2, int W2, int H2c, int W2c>
__global__ __launch_bounds__(256, 4) void conv_mfma(
    const _Float16* __restrict__ inH, const _Float16* __restrict__ inL, long inZstride,
    const _Float16* __restrict__ wt,
    float* __restrict__ out, long outZstride, float2* __restrict__ part)
{
    __shared__ __align__(16) char smem[10240];   // B dbuf: 2 x 5120; red overlay
    float2* red = (float2*)smem;                 // [64][17] after K-loop

    // ---- bijective XCD swizzle (m204) ----
    int bx;
    {
        int n = gridDim.x, orig = blockIdx.x;
        int q = n >> 3, r = n & 7;
        int xcd = orig & 7, idx = orig >> 3;
        bx = (xcd < r ? xcd * (q + 1) : r * (q + 1) + (xcd - r) * q) + idx;
    }

    const int tid  = threadIdx.x;
    const int wv   = tid >> 6;
    const int ln15 = tid & 15;
    const int lhi  = (tid >> 4) & 3;
    const int sn   = tid & 63;        // B stage: n row this thread stages
    const int skb  = tid >> 6;        // B stage: kb slot
    const int sdst = sn * 40 + skb * 8;

    const _Float16* ipH = inH + (size_t)blockIdx.z * inZstride;
    const _Float16* ipL = inL + (size_t)blockIdx.z * inZstride;

    auto pixbase = [&](int mA) -> int {
        int nb, h, w; bool valid;
        if (POOL) {
            int r = mA & 3, quad = mA >> 2;
            const int cpi = H2c * W2c;
            nb = quad / cpi;
            int rem = quad - nb * cpi;
            int h2 = rem / W2c, w2 = rem - h2 * W2c;
            h = h2 * 2 + (r >> 1); w = w2 * 2 + (r & 1);
            valid = (mA < M) && (h < Hout) && (w < Wout);
        } else {
            const int HW = Hout * Wout;
            valid = mA < M;
            int mm = valid ? mA : 0;
            nb = mm / HW;
            int rem = mm - nb * HW;
            h = rem / Wout; w = rem - h * Wout;
        }
        if (!valid) { nb = 0; h = 0; w = 0; }
        if (C1) return ((nb * 256 + h) * 256 + w) * 4;
        return ((nb * HinP + h) * WinP + w) * 64;
    };
    auto rowvalid = [&](int mA) -> bool {
        if (POOL) {
            int r = mA & 3, quad = mA >> 2;
            const int cpi = H2c * W2c;
            int nb = quad / cpi;
            int rem = quad - nb * cpi;
            int h2 = rem / W2c, w2 = rem - h2 * W2c;
            int h = h2 * 2 + (r >> 1), w = w2 * 2 + (r & 1);
            return (mA < M) && (h < Hout) && (w < Wout);
        }
        return mA < M;
    };

    int abase[2];
#pragma unroll
    for (int q = 0; q < 2; ++q)
        abase[q] = pixbase(bx * 128 + wv * 32 + q * 16 + ln15);

    unsigned vmask = 0;
#pragma unroll
    for (int q = 0; q < 2; ++q)
#pragma unroll
        for (int r = 0; r < 4; ++r)
            vmask |= (unsigned)rowvalid(bx * 128 + wv * 32 + q * 16 + lhi * 4 + r)
                     << (q * 4 + r);

    const _Float16* wp = wt + (size_t)blockIdx.z * NITER * 2048;

    auto loadA = [&](int it, f16x8 (&aH)[2], f16x8 (&aL)[2]) {
        int off;
        if (C1) off = it * 1024 + lhi * 8;
        else { int tap = it >> 1; int kh = tap / 3, kw = tap - 3 * kh;
               off = (kh * WinP + kw) * 64 + (it & 1) * 32 + lhi * 8; }
#pragma unroll
        for (int q = 0; q < 2; ++q) {
            aH[q] = *(const f16x8*)(ipH + abase[q] + off);
            aL[q] = *(const f16x8*)(ipL + abase[q] + off);
        }
    };

    f32x4 acc[2][4] = {};
    f16x8 a0H[2], a0L[2], a1H[2], a1L[2];
    f16x8 sb;

    // ---- prologue: buf0 <- B(0); a0 <- A(0); a1 <- A(1); sb <- B(1) ----
    {
        f16x8 h = *(const f16x8*)(wp + (size_t)(skb * 64 + sn) * 8);
        *(f16x8*)((_Float16*)smem + sdst) = h;
        loadA(0, a0H, a0L);
        if (NITER > 1) {
            loadA(1, a1H, a1L);
            sb = *(const f16x8*)(wp + (size_t)((4 + skb) * 64 + sn) * 8);
        }
        __syncthreads();
    }

#define REGION(IT, CUR, AH, AL)                                                   \
    {                                                                             \
        const int itc = (IT);                                                     \
        if (itc + 1 < NITER)                                                      \
            *(f16x8*)((_Float16*)(smem + ((CUR) ^ 1) * 5120) + sdst) = sb;        \
        const _Float16* rb = (const _Float16*)(smem + (CUR) * 5120);              \
        f16x8 bf[4];                                                              \
        _Pragma("unroll")                                                         \
        for (int t = 0; t < 4; ++t)                                               \
            bf[t] = *(const f16x8*)(rb + (t * 16 + ln15) * 40 + lhi * 8);         \
        if (itc + 2 < NITER)                                                      \
            sb = *(const f16x8*)(wp +                                             \
                     (size_t)(((itc + 2) * 4 + skb) * 64 + sn) * 8);              \
        _Pragma("unroll")                                                         \
        for (int t = 0; t < 4; ++t)                                               \
            _Pragma("unroll")                                                     \
            for (int q = 0; q < 2; ++q)                                           \
                acc[q][t] = __builtin_amdgcn_mfma_f32_16x16x32_f16(AH[q], bf[t], acc[q][t], 0, 0, 0); \
        _Pragma("unroll")                                                         \
        for (int t = 0; t < 4; ++t)                                               \
            _Pragma("unroll")                                                     \
            for (int q = 0; q < 2; ++q)                                           \
                acc[q][t] = __builtin_amdgcn_mfma_f32_16x16x32_f16(AL[q], bf[t], acc[q][t], 0, 0, 0); \
        if (itc + 2 < NITER) loadA(itc + 2, AH, AL);                              \
        __syncthreads();                                                          \
    }

    for (int it = 0; it < NITER; it += 2) {
        REGION(it, 0, a0H, a0L);
        if (it + 1 < NITER) REGION(it + 1, 1, a1H, a1L);
    }
#undef REGION

    // ---- per-block per-channel (sum,sumsq) partials (masked rows) ----
#pragma unroll
    for (int t = 0; t < 4; ++t) {
        float s = 0.f, s2 = 0.f;
#pragma unroll
        for (int q = 0; q < 2; ++q)
#pragma unroll
            for (int r = 0; r < 4; ++r) {
                float v = ((vmask >> (q * 4 + r)) & 1u) ? acc[q][t][r] : 0.f;
                s += v; s2 += v * v;
            }
        red[(ln15 + 16 * t) * 17 + (wv * 4 + lhi)] = make_float2(s, s2);
    }
    __syncthreads();
    if (tid < 64) {
        float s = 0.f, s2 = 0.f;
#pragma unroll
        for (int q = 0; q < 16; ++q) { float2 v = red[tid * 17 + q]; s += v.x; s2 += v.y; }
        part[((size_t)blockIdx.z * 64 + tid) * gridDim.x + bx] = make_float2(s, s2);
    }

    // ---- NHWC output ----
    float* zout = out + (size_t)blockIdx.z * outZstride;
#pragma unroll
    for (int q = 0; q < 2; ++q) {
        const int mbase = bx * 128 + wv * 32 + q * 16 + lhi * 4;
        if (POOL) {
            if (mbase < M) {
                int quad = mbase >> 2;
                const int cpi = H2c * W2c;
                int nb2  = quad / cpi;
                int rem  = quad - nb2 * cpi;
                int h2 = rem / W2c, w2 = rem - h2 * W2c;
                if (h2 < H2 && w2 < W2) {
                    float* op = zout + ((size_t)(nb2 * H2 + h2) * W2 + w2) * Cout;
#pragma unroll
                    for (int t = 0; t < 4; ++t) {
                        int n = ln15 + 16 * t;
                        if (n < Cout) {
                            float mx = fmaxf(fmaxf(acc[q][t][0], acc[q][t][1]),
                                             fmaxf(acc[q][t][2], acc[q][t][3]));
                            op[n] = mx;
                        }
                    }
                }
            }
        } else {
#pragma unroll
            for (int r = 0; r < 4; ++r) {
                int m = mbase + r;
                if (m < M) {
                    float* op = zout + (size_t)m * Cout;
#pragma unroll
                    for (int t = 0; t < 4; ++t) {
                        int n = ln15 + 16 * t;
                        if (n < Cout) op[n] = acc[q][t][r];
                    }
                }
            }
        }
    }
}

// partials -> (mean, rsqrt(var+eps)) per (z,channel)
__global__ __launch_bounds__(256) void bn_finalize(const float2* __restrict__ part,
                                                   int nblkx, double Ninv,
                                                   float2* __restrict__ stats)
{
    __shared__ double sh[512];
    const int zc = blockIdx.x, tid = threadIdx.x;
    const float2* p = part + (size_t)zc * nblkx;
    double s = 0, s2 = 0;
    for (int i = tid; i < nblkx; i += 256) { s += p[i].x; s2 += p[i].y; }
    sh[tid] = s; sh[256 + tid] = s2;
    __syncthreads();
    for (int st = 128; st > 0; st >>= 1) {
        if (tid < st) { sh[tid] += sh[tid + st]; sh[256 + tid] += sh[256 + tid + st]; }
        __syncthreads();
    }
    if (tid == 0) {
        float mean = (float)(sh[0] * Ninv);
        float var  = (float)(sh[256] * Ninv - (double)mean * (double)mean);
        if (var < 0.f) var = 0.f;
        stats[zc] = make_float2(mean, rsqrtf(var + 1e-5f));
    }
}

// raw NHWC fp32 + stats -> padded NHWC fp16 hi/lo with zero border.
__global__ void bn_split(const float* __restrict__ raw, const float2* __restrict__ stats,
                         _Float16* __restrict__ outH, _Float16* __restrict__ outL,
                         int H, int W, int total)
{
    int idx = blockIdx.x * 256 + threadIdx.x;
    if (idx >= total) return;
    const int Hp = H + 2, Wp = W + 2;
    int c4 = idx & 15;
    int t  = idx >> 4;
    int wp = t % Wp; t /= Wp;
    int hp = t % Hp; int img = t / Hp;
    size_t o = (((size_t)img * Hp + hp) * Wp + wp) * 64 + c4 * 4;
    f16x4 hi, lo;
    if (hp == 0 || hp == Hp - 1 || wp == 0 || wp == Wp - 1) {
#pragma unroll
        for (int j = 0; j < 4; ++j) { hi[j] = (_Float16)0.f; lo[j] = (_Float16)0.f; }
    } else {
        float4 v = *(const float4*)(raw + (((size_t)img * H + (hp - 1)) * W + (wp - 1)) * 64 + c4 * 4);
        const float2* st = stats + (img >> 4) * 64 + c4 * 4;
        float vv[4] = {v.x, v.y, v.z, v.w};
#pragma unroll
        for (int j = 0; j < 4; ++j) {
            float2 s = st[j];
            float r = fmaxf((vv[j] - s.x) * s.y, 0.f);
            _Float16 hh = (_Float16)r;
            hi[j] = hh; lo[j] = (_Float16)(r - (float)hh);
        }
    }
    *(f16x4*)(outH + o) = hi;
    *(f16x4*)(outL + o) = lo;
}

// pooled NHWC [P][16][H][W][64] + stats + d -> XB padded fp16 hi/lo
__global__ void mix_split(const float* __restrict__ pooled, const float2* __restrict__ stats,
                          const float* __restrict__ d,
                          _Float16* __restrict__ outH, _Float16* __restrict__ outL,
                          int H, int W, int P, long strideP, int total)
{
    int idx = blockIdx.x * 256 + threadIdx.x;
    if (idx >= total) return;
    const int Hp = H + 2, Wp = W + 2;
    int c4 = idx & 15;
    int t  = idx >> 4;
    int wp = t % Wp; t /= Wp;
    int hp = t % Hp; t /= Hp;
    int n  = t & 15;
    int cc = t >> 4;
    size_t o = (((size_t)(cc * 16 + n) * Hp + hp) * Wp + wp) * 64 + c4 * 4;
    f16x4 hi, lo;
    if (hp == 0 || hp == Hp - 1 || wp == 0 || wp == Wp - 1) {
#pragma unroll
        for (int j = 0; j < 4; ++j) { hi[j] = (_Float16)0.f; lo[j] = (_Float16)0.f; }
    } else {
        float a[4] = {0.f, 0.f, 0.f, 0.f};
        const float* pb = pooled + (((size_t)n * H + (hp - 1)) * W + (wp - 1)) * 64 + c4 * 4;
        for (int p = 0; p < P; ++p) {
            float4 v = *(const float4*)(pb + (size_t)p * strideP);
            const float2* st = stats + p * 64 + c4 * 4;
            float dc = d[cc * P + p];
            float vv[4] = {v.x, v.y, v.z, v.w};
#pragma unroll
            for (int j = 0; j < 4; ++j) {
                float2 s = st[j];
                a[j] = fmaf(dc, fmaxf((vv[j] - s.x) * s.y, 0.f), a[j]);
            }
        }
#pragma unroll
        for (int j = 0; j < 4; ++j) {
            _Float16 hh = (_Float16)a[j];
            hi[j] = hh; lo[j] = (_Float16)(a[j] - (float)hh);
        }
    }
    *(f16x4*)(outH + o) = hi;
    *(f16x4*)(outL + o) = lo;
}

// L3 mix: pooled [16][16][7][7][32] -> XB3 fp32 [40][16][7][7][32]
__global__ void mix_last(const float* __restrict__ pooled, const float2* __restrict__ stats,
                         const float* __restrict__ d, float* __restrict__ out, int total)
{
    int idx = blockIdx.x * 256 + threadIdx.x;
    if (idx >= total) return;
    int c  = idx & 31;
    int t  = idx >> 5;
    int hw = t % 49; t /= 49;
    int n  = t & 15;
    int a  = t >> 4;
    float acc = 0.f;
    const float* pb = pooled + ((size_t)n * 49 + hw) * 32 + c;
    for (int p = 0; p < 16; ++p) {
        float2 s = stats[p * 64 + c];
        acc = fmaf(d[a * 16 + p], fmaxf((pb[(size_t)p * 25088] - s.x) * s.y, 0.f), acc);
    }
    out[idx] = acc;
}

// x NCHW [16][3][256][256] -> packed NHWC4 fp16 hi/lo [16][256][256][4]
__global__ void prep_x(const float* __restrict__ x, _Float16* __restrict__ xH,
                       _Float16* __restrict__ xL)
{
    int idx = blockIdx.x * 256 + threadIdx.x;   // 16*65536
    if (idx >= 16 * 65536) return;
    int n = idx >> 16, hw = idx & 65535;
    f16x4 hi, lo;
#pragma unroll
    for (int ci = 0; ci < 3; ++ci) {
        float v = x[((size_t)n * 3 + ci) * 65536 + hw];
        _Float16 hh = (_Float16)v;
        hi[ci] = hh; lo[ci] = (_Float16)(v - (float)hh);
    }
    hi[3] = (_Float16)0.f; lo[3] = (_Float16)0.f;
    *(f16x4*)(xH + (size_t)idx * 4) = hi;
    *(f16x4*)(xL + (size_t)idx * 4) = lo;
}

// conv1 weights [64][3][7][7] -> fp16 panel [28 kblk][64][8], k=kh*32+kw*4+ci
__global__ void wtrans1(const float* __restrict__ w, _Float16* __restrict__ wt)
{
    int i = blockIdx.x * 256 + threadIdx.x;
    if (i >= 28 * 512) return;
    int j = i & 7, n = (i >> 3) & 63, kb = i >> 9;
    int k = kb * 8 + j;
    int kh = k >> 5, r = k & 31, kw = r >> 2, ci = r & 3;
    float v = (kw < 7 && ci < 3) ? w[((n * 3 + ci) * 7 + kh) * 7 + kw] : 0.f;
    wt[i] = (_Float16)v;
}

// 3x3 weights [P][Cout][64][3][3] -> fp16 panels [p][72 kblk][64][8],
// k = (kh*3+kw)*64 + ci
__global__ void wtrans3(const float* __restrict__ w, _Float16* __restrict__ wt,
                        int P, int Cout)
{
    int total = P * 72 * 512;
    for (int i = blockIdx.x * 256 + threadIdx.x; i < total; i += gridDim.x * 256) {
        int j = i & 7, n = (i >> 3) & 63, kb = (i >> 9) % 72, p = (i >> 9) / 72;
        int k = kb * 8 + j;
        int ci = k & 63, tap = k >> 6, kh = tap / 3, kw = tap - 3 * kh;
        float v = (n < Cout) ? w[(((size_t)(p * Cout + n)) * 64 + ci) * 9 + kh * 3 + kw] : 0.f;
        wt[i] = (_Float16)v;
    }
}

// d = softmax_p( log(softmax_p(br*2)) / t ) for all 4 layers
__global__ void dcalc(const float* __restrict__ br0, const float* __restrict__ br1,
                      const float* __restrict__ br2, const float* __restrict__ br3,
                      const void* __restrict__ tptr, float* __restrict__ D)
{
    const int L = blockIdx.x;
    const float* br; int C, P, off;
    if      (L == 0) { br = br0; C = 4;  P = 2;  off = 0;   }
    else if (L == 1) { br = br1; C = 8;  P = 4;  off = 8;   }
    else if (L == 2) { br = br2; C = 16; P = 8;  off = 40;  }
    else             { br = br3; C = 40; P = 16; off = 168; }
    int ti = *(const int*)tptr;
    float t = (ti > 0 && ti < 1000000) ? (float)ti : *(const float*)tptr;
    const int c = threadIdx.x;
    if (c >= C) return;
    float u[16];
    float mx = -1e30f;
#pragma unroll
    for (int p = 0; p < 16; ++p) if (p < P) { u[p] = br[c * P + p] * 2.0f; mx = fmaxf(mx, u[p]); }
    float se = 0.f;
#pragma unroll
    for (int p = 0; p < 16; ++p) if (p < P) se += expf(u[p] - mx);
    float lse = mx + logf(se);
    float mx2 = -1e30f;
#pragma unroll
    for (int p = 0; p < 16; ++p) if (p < P) { u[p] = (u[p] - lse) / t; mx2 = fmaxf(mx2, u[p]); }
    float se2 = 0.f;
#pragma unroll
    for (int p = 0; p < 16; ++p) if (p < P) { u[p] = expf(u[p] - mx2); se2 += u[p]; }
#pragma unroll
    for (int p = 0; p < 16; ++p) if (p < P) D[off + c * P + p] = u[p] / se2;
}

// h1[a,b,i] = relu( sum_f f[a,b,f]*fw1[a,f,i] + fb1[a,i] ); f stored (h,w,c),
// fw1 indexed (c,h,w)
__global__ __launch_bounds__(128) void fc1_k(const float* __restrict__ f,
                                             const float* __restrict__ w1,
                                             const float* __restrict__ b1,
                                             float* __restrict__ h1)
{
    const int a = blockIdx.x >> 4;
    const int b = blockIdx.x & 15;
    const int i = threadIdx.x;
    const float* fv = f + ((size_t)a * 16 + b) * 1568;
    const float* wv = w1 + (size_t)a * 1568 * 128 + i;
    float acc = b1[a * 128 + i];
    for (int hw = 0; hw < 49; ++hw)
        for (int c = 0; c < 32; ++c)
            acc = fmaf(fv[hw * 32 + c], wv[(size_t)(c * 49 + hw) * 128], acc);
    h1[((size_t)a * 16 + b) * 128 + i] = fmaxf(acc, 0.f);
}

__global__ __launch_bounds__(128) void fc23_k(const float* __restrict__ h1,
                                              const float* __restrict__ w2,
                                              const float* __restrict__ b2,
                                              const float* __restrict__ w3,
                                              const float* __restrict__ b3,
                                              float* __restrict__ out)
{
    __shared__ float sh1[16][128];
    __shared__ float sh2[16][128];
    const int a = blockIdx.x;
    const int i = threadIdx.x;
    for (int b = 0; b < 16; ++b) sh1[b][i] = h1[((size_t)a * 16 + b) * 128 + i];
    __syncthreads();
    float acc[16];
#pragma unroll
    for (int b = 0; b < 16; ++b) acc[b] = b2[a * 128 + i];
    for (int ff = 0; ff < 128; ++ff) {
        float wv = w2[((size_t)a * 128 + ff) * 128 + i];
#pragma unroll
        for (int b = 0; b < 16; ++b) acc[b] = fmaf(sh1[b][ff], wv, acc[b]);
    }
    for (int b = 0; b < 16; ++b) sh2[b][i] = fmaxf(acc[b], 0.f);
    __syncthreads();
    if (i < 16) {
        float o = b3[a];
        for (int ff = 0; ff < 128; ++ff) o = fmaf(sh2[i][ff], w3[a * 128 + ff], o);
        out[i * 40 + a] = o;
    }
}

extern "C" void kernel_launch(void* const* d_in, const int* in_sizes, int n_in,
                              void* d_out, int out_size, void* d_ws, size_t ws_size,
                              hipStream_t stream)
{
    (void)in_sizes; (void)n_in;

    const float* x   = (const float*)d_in[0];
    const float* w10 = (const float*)d_in[1];
    const float* wa[4] = {(const float*)d_in[3],  (const float*)d_in[7],
                          (const float*)d_in[11], (const float*)d_in[15]};
    const float* wb[4] = {(const float*)d_in[5],  (const float*)d_in[9],
                          (const float*)d_in[13], (const float*)d_in[17]};
    const float* br[4] = {(const float*)d_in[19], (const float*)d_in[20],
                          (const float*)d_in[21], (const float*)d_in[22]};
    const float* fw1 = (const float*)d_in[23];
    const float* fb1 = (const float*)d_in[24];
    const float* fw2 = (const float*)d_in[25];
    const float* fb2 = (const float*)d_in[26];
    const float* fw3 = (const float*)d_in[27];
    const float* fb3 = (const float*)d_in[28];
    float* out = (float*)d_out;

    const int Pl[4]  = {2, 4, 8, 16};
    const int CBs[4] = {64, 64, 64, 32};

    // ---- workspace arenas (f32 units); total 59,151,616 f32 = 236.6 MB ----
    const size_t NEED = 59151616ull * 4ull;
    if (ws_size < NEED) {
        hipMemsetAsync(d_out, 0, (size_t)out_size * sizeof(float), stream);
        return;
    }
    float* ws = (float*)d_ws;
    size_t o = 0;
    _Float16* WT1 = (_Float16*)(ws + o); o += 7168;
    _Float16 *WTA[4], *WTB[4];
    for (int L = 0; L < 4; ++L) {
        WTA[L] = (_Float16*)(ws + o); o += (size_t)Pl[L] * 18432;
        WTB[L] = (_Float16*)(ws + o); o += (size_t)Pl[L] * 18432;
    }
    float*  D     = ws + o; o += 1024;
    float2* STATS = (float2*)(ws + o); o += 4352;
    float2* STATS_C1 = STATS;
    float2* STATS_A  = STATS + 64;
    float2* STATS_B  = STATS + 1088;
    float*  H1 = ws + o; o += 81920;
    float*  A6 = ws + o; o += 524288;
    float*  A5 = ws + o; o += 7872512;
    float*  A4 = ws + o; o += 16000000;
    float*  A3 = ws + o; o += 16777216;
    float*  A2 = ws + o; o += 16777216;

    float2* PART   = (float2*)A6;
    float2* PARTC1 = (float2*)A5;
    _Float16* xcH = (_Float16*)A3;
    _Float16* xcL = (_Float16*)(A3 + 2097152);
    _Float16* A2H = (_Float16*)A2;
    _Float16* A2L = (_Float16*)(A2 + 8388608);
    _Float16* A3H = (_Float16*)A3;
    _Float16* A3L = (_Float16*)(A3 + 8388608);

    // ---- weights + mix coefficients + conv1 input prep ----
    prep_x<<<4096, 256, 0, stream>>>(x, xcH, xcL);
    wtrans1<<<56, 256, 0, stream>>>(w10, WT1);
    for (int L = 0; L < 4; ++L) {
        int tA = Pl[L] * 72 * 512;
        wtrans3<<<DIVUP(tA, 256), 256, 0, stream>>>(wa[L], WTA[L], Pl[L], 64);
        wtrans3<<<DIVUP(tA, 256), 256, 0, stream>>>(wb[L], WTB[L], Pl[L], CBs[L]);
    }
    dcalc<<<4, 64, 0, stream>>>(br[0], br[1], br[2], br[3], d_in[29], D);

    // ---- conv1: xc -> pooled raw A4 [16,125,125,64] + stats ----
    conv_mfma<1, 1, 256, 256, 250, 250, 64, 1000000, 7, 125, 125, 125, 125>
        <<<dim3(7813, 1, 1), 256, 0, stream>>>(xcH, xcL, 0, WT1, A4, 0, PARTC1);
    bn_finalize<<<64, 256, 0, stream>>>(PARTC1, 7813, 1.0 / 1000000.0, STATS_C1);
    bn_split<<<DIVUP(16 * 127 * 127 * 16, 256), 256, 0, stream>>>(
        A4, STATS_C1, A2H, A2L, 125, 125, 16 * 127 * 127 * 16);

    // ---- layer 0 (per parent; Y shared) ----
    for (int p = 0; p < 2; ++p) {
        conv_mfma<0, 0, 127, 127, 125, 125, 64, 250000, 18, 0, 0, 1, 1>
            <<<dim3(1954, 1, 1), 256, 0, stream>>>(
                A2H, A2L, 0, WTA[0] + (size_t)p * 36864, A4, 0, PART);
        bn_finalize<<<64, 256, 0, stream>>>(PART, 1954, 1.0 / 250000.0, STATS_A);
        bn_split<<<DIVUP(16 * 127 * 127 * 16, 256), 256, 0, stream>>>(
            A4, STATS_A, A3H, A3L, 125, 125, 16 * 127 * 127 * 16);
        conv_mfma<1, 0, 127, 127, 125, 125, 64, 254016, 18, 62, 62, 63, 63>
            <<<dim3(1985, 1, 1), 256, 0, stream>>>(
                A3H, A3L, 0, WTB[0] + (size_t)p * 36864, A5 + (size_t)p * 3936256, 0, PART);
        bn_finalize<<<64, 256, 0, stream>>>(PART, 1985, 1.0 / 250000.0, STATS_B + p * 64);
    }
    mix_split<<<DIVUP(4 * 16 * 64 * 64 * 16, 256), 256, 0, stream>>>(
        A5, STATS_B, D + 0, A2H, A2L, 62, 62, 2, 3936256, 4 * 16 * 64 * 64 * 16);

    // ---- layer 1 (z=4) ----
    conv_mfma<0, 0, 64, 64, 62, 62, 64, 61504, 18, 0, 0, 1, 1>
        <<<dim3(481, 1, 4), 256, 0, stream>>>(
            A2H, A2L, 4194304, WTA[1], A4, 3936256, PART);
    bn_finalize<<<256, 256, 0, stream>>>(PART, 481, 1.0 / 61504.0, STATS_A);
    bn_split<<<DIVUP(64 * 64 * 64 * 16, 256), 256, 0, stream>>>(
        A4, STATS_A, A3H, A3L, 62, 62, 64 * 64 * 64 * 16);
    conv_mfma<1, 0, 64, 64, 62, 62, 64, 61504, 18, 31, 31, 31, 31>
        <<<dim3(481, 1, 4), 256, 0, stream>>>(
            A3H, A3L, 4194304, WTB[1], A5, 984064, PART);
    bn_finalize<<<256, 256, 0, stream>>>(PART, 481, 1.0 / 61504.0, STATS_B);
    mix_split<<<DIVUP(8 * 16 * 33 * 33 * 16, 256), 256, 0, stream>>>(
        A5, STATS_B, D + 8, A2H, A2L, 31, 31, 4, 984064, 8 * 16 * 33 * 33 * 16);

    // ---- layer 2 (z=8) ----
    conv_mfma<0, 0, 33, 33, 31, 31, 64, 15376, 18, 0, 0, 1, 1>
        <<<dim3(121, 1, 8), 256, 0, stream>>>(
            A2H, A2L, 1115136, WTA[2], A4, 984064, PART);
    bn_finalize<<<512, 256, 0, stream>>>(PART, 121, 1.0 / 15376.0, STATS_A);
    bn_split<<<DIVUP(128 * 33 * 33 * 16, 256), 256, 0, stream>>>(
        A4, STATS_A, A3H, A3L, 31, 31, 128 * 33 * 33 * 16);
    conv_mfma<1, 0, 33, 33, 31, 31, 64, 16384, 18, 15, 15, 16, 16>
        <<<dim3(128, 1, 8), 256, 0, stream>>>(
            A3H, A3L, 1115136, WTB[2], A5, 230400, PART);
    bn_finalize<<<512, 256, 0, stream>>>(PART, 128, 1.0 / 15376.0, STATS_B);
    mix_split<<<DIVUP(16 * 16 * 17 * 17 * 16, 256), 256, 0, stream>>>(
        A5, STATS_B, D + 40, A2H, A2L, 15, 15, 8, 230400, 16 * 16 * 17 * 17 * 16);

    // ---- layer 3 (z=16) ----
    conv_mfma<0, 0, 17, 17, 15, 15, 64, 3600, 18, 0, 0, 1, 1>
        <<<dim3(29, 1, 16), 256, 0, stream>>>(
            A2H, A2L, 295936, WTA[3], A4, 230400, PART);
    bn_finalize<<<1024, 256, 0, stream>>>(PART, 29, 1.0 / 3600.0, STATS_A);
    bn_split<<<DIVUP(256 * 17 * 17 * 16, 256), 256, 0, stream>>>(
        A4, STATS_A, A3H, A3L, 15, 15, 256 * 17 * 17 * 16);
    conv_mfma<1, 0, 17, 17, 15, 15, 32, 4096, 18, 7, 7, 8, 8>
        <<<dim3(32, 1, 16), 256, 0, stream>>>(
            A3H, A3L, 295936, WTB[3], A5, 25088, PART);
    bn_finalize<<<1024, 256, 0, stream>>>(PART, 32, 1.0 / 3600.0, STATS_B);
    mix_last<<<DIVUP(40 * 16 * 49 * 32, 256), 256, 0, stream>>>(
        A5, STATS_B, D + 168, A2, 40 * 16 * 49 * 32);

    // ---- FC heads ----
    fc1_k<<<640, 128, 0, stream>>>(A2, fw1, fb1, H1);
    fc23_k<<<40, 128, 0, stream>>>(H1, fw2, fb2, fw3, fb3, out);
}